// Round 8
// baseline (1421.713 us; speedup 1.0000x reference)
//
#include <hip/hip_runtime.h>
#include <hip/hip_bf16.h>

#define T_STEPS 512
#define BATCH   1024
#define HD1     80
#define HD2     100

#define W1_DW   (HD1 / 2)              // 40 packed dwords per lstm1 row
#define NR1     (4 * HD1)              // 320 rows
#define NR2     (4 * HD2)              // 400 rows

// ---- lstm2 MFMA geometry ----
#define NB2     16                     // batches per block (MFMA N=16)
#define NKT     6                      // k-tiles of 32 (K = 192 = 80 h1 + 100 h2 + 12 pad)
#define NUT     7                      // unit-tiles per gate (112 padded units)
#define NTILES  (4 * NUT)              // 28 row-tiles of 16
#define W2F_DW  (NTILES * NKT * 64 * 4) // 43008 dwords of packed A-fragments

// ---- chunked h1 staging (R8) ----
#define CH      16                     // steps per chunk
#define NCH     (T_STEPS / CH)         // 32 chunks
#define LINE_H  1280                   // halfs per (t,bg) h1 line: 10 groups x 16 x 8
#define H2G     14                     // h2 groups (k=80..191): groups 10..23

typedef _Float16 half2_t __attribute__((ext_vector_type(2)));
typedef _Float16 f16x4   __attribute__((ext_vector_type(4)));
typedef _Float16 f16x8   __attribute__((ext_vector_type(8)));
typedef float    f32x4   __attribute__((ext_vector_type(4)));

union HU { unsigned int u; half2_t h; };
static __device__ __forceinline__ half2_t bch(unsigned int u) { HU x; x.u = u; return x.h; }
static __device__ __forceinline__ unsigned int bcu(half2_t h) { HU x; x.h = h; return x.u; }

static __device__ __forceinline__ float dot2(half2_t a, half2_t b, float c) {
    return __builtin_amdgcn_fdot2(a, b, c, false);
}

static __device__ __forceinline__ unsigned int packh(float a, float b) {
    half2_t p; p.x = (_Float16)a; p.y = (_Float16)b; return bcu(p);
}

// async global->LDS, 16B per lane; LDS dest = uniform base + lane*16 (HW)
static __device__ __forceinline__ void gld_lds16(const void* g, void* l) {
    __builtin_amdgcn_global_load_lds(
        (const __attribute__((address_space(1))) unsigned int*)g,
        (__attribute__((address_space(3))) unsigned int*)l, 16, 0, 0);
}

// ---------------------------------------------------------------------------
// Prep (unchanged from R7): w1t lstm1 packed dwords; w2f gate-padded A-frags.
// ---------------------------------------------------------------------------
__global__ __launch_bounds__(256)
void prep_kernel(const float* __restrict__ W_hh1,
                 const float* __restrict__ W_ih2,
                 const float* __restrict__ W_hh2,
                 unsigned int* __restrict__ w1t,
                 unsigned int* __restrict__ w2f)
{
    int i = blockIdx.x * 256 + threadIdx.x;
    if (i < W1_DW * NR1) {
        int d = i / NR1, j = i % NR1;
        w1t[i] = packh(W_hh1[j * HD1 + 2 * d], W_hh1[j * HD1 + 2 * d + 1]);
    } else if (i < W1_DW * NR1 + W2F_DW) {
        int d  = i - W1_DW * NR1;
        int H  = 2 * d;
        int s  = H % 8;
        int l  = (H / 8) % 64;
        int kt = (H / 512) % NKT;
        int tile = H / 3072;                   // 0..27
        int g  = tile / NUT;
        int j  = tile % NUT;
        int up = j * 16 + (l & 15);
        int k  = kt * 32 + (l >> 4) * 8 + s;
        float v0 = 0.f, v1 = 0.f;
        if (up < HD2) {
            int r = g * HD2 + up;
            v0 = (k < HD1) ? W_ih2[r * HD1 + k]
               : (k < HD1 + HD2) ? W_hh2[r * HD2 + (k - HD1)] : 0.f;
            int k1 = k + 1;
            v1 = (k1 < HD1) ? W_ih2[r * HD1 + k1]
               : (k1 < HD1 + HD2) ? W_hh2[r * HD2 + (k1 - HD1)] : 0.f;
        }
        w2f[d] = packh(v0, v1);
    }
}

// ---------------------------------------------------------------------------
// Phase 1: LSTM layer 1 (R4 structure). R8 CHANGE: writes h1relu directly in
// lstm2's B-fragment chunk layout [chunk][bg][tc][k>>3][bt][k&7] so lstm2
// can bulk-DMA whole 40KB chunks with global_load_lds. Writer+reader share
// this gauge; any mismatch shows in absmax.
// ---------------------------------------------------------------------------
__global__ __launch_bounds__(NR1, 4)
void lstm1_kernel(const float* __restrict__ x,
                  const float* __restrict__ W_ih1,
                  const unsigned int* __restrict__ w1t,
                  const float* __restrict__ b_ih1,
                  const float* __restrict__ b_hh1,
                  _Float16* __restrict__ h1relu)
{
    const int j = threadIdx.x;
    const int b = blockIdx.x;
    const int q = j / HD1;
    const int m = j % HD1;
    const int bg = b >> 4, bt = b & 15;

    unsigned int w[W1_DW];
#pragma unroll
    for (int d = 0; d < W1_DW; d++) w[d] = w1t[d * NR1 + j];
    const float wih  = W_ih1[j];
    const float bias = b_ih1[j] + b_hh1[j];

    __shared__ uint4 hp[HD1 / 8];
    __shared__ float gates[NR1];
    __shared__ float xs[T_STEPS];

    if (j < HD1 / 8) hp[j] = make_uint4(0u, 0u, 0u, 0u);
    for (int idx = j; idx < T_STEPS; idx += NR1)
        xs[idx] = x[(size_t)b * T_STEPS + idx];
    float c = 0.f;
    __syncthreads();

    for (int t = 0; t < T_STEPS; t++) {
        float accP = fmaf(wih, xs[t], bias);
        float accQ = 0.f;
#pragma unroll
        for (int k4 = 0; k4 < HD1 / 8; k4++) {
            uint4 U = hp[k4];
            accP = dot2(bch(w[4 * k4 + 0]), bch(U.x), accP);
            accQ = dot2(bch(w[4 * k4 + 1]), bch(U.y), accQ);
            accP = dot2(bch(w[4 * k4 + 2]), bch(U.z), accP);
            accQ = dot2(bch(w[4 * k4 + 3]), bch(U.w), accQ);
        }
        float z = accP + accQ;
        z = (q == 2) ? 2.f * z : z;
        float s = 1.f / (1.f + __expf(-z));
        gates[j] = (q == 2) ? (2.f * s - 1.f) : s;
        __syncthreads();

        if (j < HD1) {
            float gi = gates[m];
            float gf = gates[HD1 + m];
            float gg = gates[2 * HD1 + m];
            float go = gates[3 * HD1 + m];
            c = fmaf(gf, c, gi * gg);
            float th = 2.f / (1.f + __expf(-2.f * c)) - 1.f;
            float h = go * th;
            float hn = __shfl_down(h, 1, 64);
            if ((m & 1) == 0) {
                ((unsigned int*)hp)[m >> 1] = packh(h, hn);
                // chunk layout: ((ch*64+bg)*CH+tc)*1280 + (m>>3)*128 + bt*8 + (m&7)
                size_t off = (((size_t)(t >> 4) * 64 + bg) * CH + (t & 15)) * LINE_H
                           + (m >> 3) * 128 + bt * 8 + (m & 7);
                *(unsigned int*)(h1relu + off) = packh(fmaxf(h, 0.f), fmaxf(hn, 0.f));
            }
        }
        __syncthreads();
    }
}

// ---------------------------------------------------------------------------
// Phase 2: LSTM layer 2 — MFMA, in-register gates, CHUNKED async h1 staging.
//
// R8 RATIONALE: R7 counters (VALUBusy 17%, 3940 cy/step vs ~670 busy) point
// at the per-step barrier drain: the stager's 10 global loads/step force
// s_waitcnt vmcnt(0) before every s_barrier -> whole block eats an HBM/L3
// round-trip each step. Fix: h1 has no recurrence -> stage it in 16-step
// 40KB chunks with global_load_lds (40 coalesced 1KB issues, one drain per
// chunk instead of per step). h2 keeps a per-step LDS double-buffer written
// directly by workers. One barrier/step, worker math identical to R7.
// ---------------------------------------------------------------------------
__global__ __launch_bounds__(512, 1)
void lstm2_kernel(const _Float16* __restrict__ h1relu,
                  const _Float16* __restrict__ w2f,
                  const float* __restrict__ b_ih2,
                  const float* __restrict__ b_hh2,
                  float* __restrict__ h2last)
{
    const int tid = threadIdx.x;
    const int l   = tid & 63;
    const int wv  = tid >> 6;              // 0..7
    const int bg  = blockIdx.x;            // batch group (16 batches)
    const int b0  = bg * NB2;
    const int bt  = l & 15;
    const int u0  = wv * 16 + ((l >> 4) << 2);
    const bool workerWave = (wv < 7);
    const bool worker = workerWave && (u0 < HD2);

    __shared__ _Float16 chunkbuf[2][CH * LINE_H];  // 2 x 40KB h1 chunks
    __shared__ _Float16 h2buf[2][H2G * 128];       // 2 x 3.5KB h2 frags

    // persistent A-fragments
    const int wvc = workerWave ? wv : 6;
    f16x8 a[4][NKT];
#pragma unroll
    for (int g = 0; g < 4; g++)
#pragma unroll
        for (int kt = 0; kt < NKT; kt++)
            a[g][kt] = *(const f16x8*)(w2f +
                ((size_t)((g * NUT + wvc) * NKT + kt) * 64 + l) * 8);

    float bs[4][4];
#pragma unroll
    for (int g = 0; g < 4; g++)
#pragma unroll
        for (int r = 0; r < 4; r++) {
            int uu = (u0 + r < HD2) ? (u0 + r) : 0;
            bs[g][r] = b_ih2[g * HD2 + uu] + b_hh2[g * HD2 + uu];
        }

    float c[4] = {0.f, 0.f, 0.f, 0.f};

    // zero h2 buffers (incl. pad groups 22/23) : 1792 dwords
    for (int i = tid; i < H2G * 128; i += 512) ((unsigned int*)h2buf)[i] = 0u;

    // prologue: DMA chunk 0 into chunkbuf[0]
    if (wv == 7) {
        const _Float16* g = h1relu + (size_t)bg * CH * LINE_H + l * 8;
#pragma unroll
        for (int i = 0; i < 40; i++)
            gld_lds16(g + i * 512, &chunkbuf[0][i * 512]);
    }
    __syncthreads();   // drains DMA + covers zeroing

    int cur = 0;
    for (int t = 0; t < T_STEPS; t++) {
        const int tc = t & (CH - 1);
        const int cb = (t >> 4) & 1;

        if (workerWave) {
            const _Float16* ck = &chunkbuf[cb][tc * LINE_H];
            f16x8 bfr[NKT];
#pragma unroll
            for (int kt = 0; kt < NKT; kt++) {
                int gi = kt * 4 + (l >> 4);
                const _Float16* src = (gi < 10)
                    ? (ck + gi * 128 + bt * 8)
                    : (&h2buf[cur][0] + (gi - 10) * 128 + bt * 8);
                bfr[kt] = *(const f16x8*)src;
            }

            f32x4 acc[4];
#pragma unroll
            for (int g = 0; g < 4; g++) {
                f32x4 z4 = {0.f, 0.f, 0.f, 0.f};
#pragma unroll
                for (int kt = 0; kt < NKT; kt++)
                    z4 = __builtin_amdgcn_mfma_f32_16x16x32_f16(
                             a[g][kt], bfr[kt], z4, 0, 0, 0);
                acc[g] = z4;
            }

            if (worker) {
                f16x4 hh;
#pragma unroll
                for (int r = 0; r < 4; r++) {
                    float zi = acc[0][r] + bs[0][r];
                    float zf = acc[1][r] + bs[1][r];
                    float zg = acc[2][r] + bs[2][r];
                    float zo = acc[3][r] + bs[3][r];
                    float gi = 1.f / (1.f + __expf(-zi));
                    float gf = 1.f / (1.f + __expf(-zf));
                    float gg = 2.f / (1.f + __expf(-2.f * zg)) - 1.f;
                    float go = 1.f / (1.f + __expf(-zo));
                    c[r] = fmaf(gf, c[r], gi * gg);
                    float th = 2.f / (1.f + __expf(-2.f * c[r])) - 1.f;
                    float h = go * th;
                    hh[r] = (_Float16)h;
                    if (t == T_STEPS - 1)
                        h2last[(size_t)(b0 + bt) * HD2 + u0 + r] = fmaxf(h, 0.f);
                }
                int k0 = HD1 + u0;             // k0&7 in {0,4}
                *(f16x4*)&h2buf[cur ^ 1][((k0 >> 3) - 10) * 128 + bt * 8 + (k0 & 7)] = hh;
            }
        } else {
            // stager wave: once per chunk, DMA next chunk (one drain/chunk)
            if (tc == 0 && (t >> 4) + 1 < NCH) {
                const _Float16* g = h1relu +
                    ((size_t)((t >> 4) + 1) * 64 + bg) * CH * LINE_H + l * 8;
                _Float16* dst = &chunkbuf[cb ^ 1][0];
#pragma unroll
                for (int i = 0; i < 40; i++)
                    gld_lds16(g + i * 512, dst + i * 512);
            }
        }
        __syncthreads();                       // single barrier per step
        cur ^= 1;
    }
}

// ---------------------------------------------------------------------------
// Head: out[b] = W_l2 @ relu(W_l1 @ h2last[b] + b_l1) + b_l2
// ---------------------------------------------------------------------------
__global__ __launch_bounds__(64)
void head_kernel(const float* __restrict__ h2last,
                 const float* __restrict__ W_l1,
                 const float* __restrict__ b_l1,
                 const float* __restrict__ W_l2,
                 const float* __restrict__ b_l2,
                 float* __restrict__ out)
{
    int b = blockIdx.x * 64 + threadIdx.x;
    if (b >= BATCH) return;
    const float* h = h2last + (size_t)b * HD2;
    float o = b_l2[0];
#pragma unroll
    for (int u = 0; u < 10; u++) {
        float s = b_l1[u];
#pragma unroll
        for (int k = 0; k < HD2; k++) s = fmaf(W_l1[u * HD2 + k], h[k], s);
        o = fmaf(W_l2[u], fmaxf(s, 0.f), o);
    }
    out[b] = o;
}

extern "C" void kernel_launch(void* const* d_in, const int* in_sizes, int n_in,
                              void* d_out, int out_size, void* d_ws, size_t ws_size,
                              hipStream_t stream)
{
    const float* x     = (const float*)d_in[0];
    const float* W_ih1 = (const float*)d_in[1];
    const float* W_hh1 = (const float*)d_in[2];
    const float* b_ih1 = (const float*)d_in[3];
    const float* b_hh1 = (const float*)d_in[4];
    const float* W_ih2 = (const float*)d_in[5];
    const float* W_hh2 = (const float*)d_in[6];
    const float* b_ih2 = (const float*)d_in[7];
    const float* b_hh2 = (const float*)d_in[8];
    const float* W_l1  = (const float*)d_in[9];
    const float* b_l1  = (const float*)d_in[10];
    const float* W_l2  = (const float*)d_in[11];
    const float* b_l2  = (const float*)d_in[12];
    float* out = (float*)d_out;

    // ws layout: h1relu f16 chunk-layout (84 MB) | h2last f32 | w1t | w2f
    char* p = (char*)d_ws;
    _Float16* h1relu = (_Float16*)p;           p += (size_t)T_STEPS * BATCH * HD1 * 2;
    float* h2last    = (float*)p;              p += (size_t)BATCH * HD2 * 4;
    unsigned int* w1t = (unsigned int*)p;      p += (size_t)W1_DW * NR1 * 4;
    unsigned int* w2fu = (unsigned int*)p;

    int prep_n = W1_DW * NR1 + W2F_DW;
    hipLaunchKernelGGL(prep_kernel, dim3((prep_n + 255) / 256), dim3(256), 0, stream,
                       W_hh1, W_ih2, W_hh2, w1t, w2fu);
    hipLaunchKernelGGL(lstm1_kernel, dim3(BATCH), dim3(NR1), 0, stream,
                       x, W_ih1, w1t, b_ih1, b_hh1, h1relu);
    hipLaunchKernelGGL(lstm2_kernel, dim3(BATCH / NB2), dim3(512), 0, stream,
                       h1relu, (const _Float16*)w2fu, b_ih2, b_hh2, h2last);
    hipLaunchKernelGGL(head_kernel, dim3(BATCH / 64), dim3(64), 0, stream,
                       h2last, W_l1, b_l1, W_l2, b_l2, out);
}

// Round 9
// 1415.400 us; speedup vs baseline: 1.0045x; 1.0045x over previous
//
#include <hip/hip_runtime.h>
#include <hip/hip_bf16.h>

#define T_STEPS 512
#define BATCH   1024
#define HD1     80
#define HD2     100

#define W1_DW   (HD1 / 2)              // 40 packed dwords per lstm1 row
#define NR1     (4 * HD1)              // 320 rows
#define NR2     (4 * HD2)              // 400 rows

// ---- lstm2 MFMA geometry ----
#define NB2     16                     // batches per block (MFMA N=16)
#define NKT     6                      // k-tiles of 32 (K = 192 = 80 h1 + 100 h2 + 12 pad)
#define NUT     7                      // unit-tiles per gate (112 padded units)
#define NTILES  (4 * NUT)              // 28 row-tiles of 16
#define W2F_DW  (NTILES * NKT * 64 * 4) // 43008 dwords of packed A-fragments

// ---- chunked h1 staging ----
#define CH      16                     // steps per chunk
#define NCH     (T_STEPS / CH)         // 32 chunks
#define LINE_H  1280                   // halfs per (t,bg) h1 line: 10 groups x 16 x 8
#define H2G     14                     // h2 groups (k=80..191): groups 10..23

typedef _Float16 half2_t __attribute__((ext_vector_type(2)));
typedef _Float16 f16x4   __attribute__((ext_vector_type(4)));
typedef _Float16 f16x8   __attribute__((ext_vector_type(8)));
typedef float    f32x4   __attribute__((ext_vector_type(4)));

union HU { unsigned int u; half2_t h; };
static __device__ __forceinline__ half2_t bch(unsigned int u) { HU x; x.u = u; return x.h; }
static __device__ __forceinline__ unsigned int bcu(half2_t h) { HU x; x.h = h; return x.u; }

static __device__ __forceinline__ float dot2(half2_t a, half2_t b, float c) {
    return __builtin_amdgcn_fdot2(a, b, c, false);
}

static __device__ __forceinline__ unsigned int packh(float a, float b) {
    half2_t p; p.x = (_Float16)a; p.y = (_Float16)b; return bcu(p);
}

// Force a value to stay resident in VGPRs: opaque read-write asm means the
// compiler cannot rematerialize it from its (pure) defining load. (rule #17)
static __device__ __forceinline__ void pin(f16x8& x) {
    asm volatile("" : "+v"(x));
}

// async global->LDS, 16B per lane; LDS dest = uniform base + lane*16 (HW)
static __device__ __forceinline__ void gld_lds16(const void* g, void* l) {
    __builtin_amdgcn_global_load_lds(
        (const __attribute__((address_space(1))) unsigned int*)g,
        (__attribute__((address_space(3))) unsigned int*)l, 16, 0, 0);
}

// ---------------------------------------------------------------------------
// Prep (unchanged): w1t lstm1 packed dwords; w2f gate-padded A-frags.
// ---------------------------------------------------------------------------
__global__ __launch_bounds__(256)
void prep_kernel(const float* __restrict__ W_hh1,
                 const float* __restrict__ W_ih2,
                 const float* __restrict__ W_hh2,
                 unsigned int* __restrict__ w1t,
                 unsigned int* __restrict__ w2f)
{
    int i = blockIdx.x * 256 + threadIdx.x;
    if (i < W1_DW * NR1) {
        int d = i / NR1, j = i % NR1;
        w1t[i] = packh(W_hh1[j * HD1 + 2 * d], W_hh1[j * HD1 + 2 * d + 1]);
    } else if (i < W1_DW * NR1 + W2F_DW) {
        int d  = i - W1_DW * NR1;
        int H  = 2 * d;
        int s  = H % 8;
        int l  = (H / 8) % 64;
        int kt = (H / 512) % NKT;
        int tile = H / 3072;                   // 0..27
        int g  = tile / NUT;
        int j  = tile % NUT;
        int up = j * 16 + (l & 15);
        int k  = kt * 32 + (l >> 4) * 8 + s;
        float v0 = 0.f, v1 = 0.f;
        if (up < HD2) {
            int r = g * HD2 + up;
            v0 = (k < HD1) ? W_ih2[r * HD1 + k]
               : (k < HD1 + HD2) ? W_hh2[r * HD2 + (k - HD1)] : 0.f;
            int k1 = k + 1;
            v1 = (k1 < HD1) ? W_ih2[r * HD1 + k1]
               : (k1 < HD1 + HD2) ? W_hh2[r * HD2 + (k1 - HD1)] : 0.f;
        }
        w2f[d] = packh(v0, v1);
    }
}

// ---------------------------------------------------------------------------
// Phase 1: LSTM layer 1 (unchanged; writes h1relu in lstm2's chunk layout).
// ---------------------------------------------------------------------------
__global__ __launch_bounds__(NR1, 4)
void lstm1_kernel(const float* __restrict__ x,
                  const float* __restrict__ W_ih1,
                  const unsigned int* __restrict__ w1t,
                  const float* __restrict__ b_ih1,
                  const float* __restrict__ b_hh1,
                  _Float16* __restrict__ h1relu)
{
    const int j = threadIdx.x;
    const int b = blockIdx.x;
    const int q = j / HD1;
    const int m = j % HD1;
    const int bg = b >> 4, bt = b & 15;

    unsigned int w[W1_DW];
#pragma unroll
    for (int d = 0; d < W1_DW; d++) w[d] = w1t[d * NR1 + j];
    const float wih  = W_ih1[j];
    const float bias = b_ih1[j] + b_hh1[j];

    __shared__ uint4 hp[HD1 / 8];
    __shared__ float gates[NR1];
    __shared__ float xs[T_STEPS];

    if (j < HD1 / 8) hp[j] = make_uint4(0u, 0u, 0u, 0u);
    for (int idx = j; idx < T_STEPS; idx += NR1)
        xs[idx] = x[(size_t)b * T_STEPS + idx];
    float c = 0.f;
    __syncthreads();

    for (int t = 0; t < T_STEPS; t++) {
        float accP = fmaf(wih, xs[t], bias);
        float accQ = 0.f;
#pragma unroll
        for (int k4 = 0; k4 < HD1 / 8; k4++) {
            uint4 U = hp[k4];
            accP = dot2(bch(w[4 * k4 + 0]), bch(U.x), accP);
            accQ = dot2(bch(w[4 * k4 + 1]), bch(U.y), accQ);
            accP = dot2(bch(w[4 * k4 + 2]), bch(U.z), accP);
            accQ = dot2(bch(w[4 * k4 + 3]), bch(U.w), accQ);
        }
        float z = accP + accQ;
        z = (q == 2) ? 2.f * z : z;
        float s = 1.f / (1.f + __expf(-z));
        gates[j] = (q == 2) ? (2.f * s - 1.f) : s;
        __syncthreads();

        if (j < HD1) {
            float gi = gates[m];
            float gf = gates[HD1 + m];
            float gg = gates[2 * HD1 + m];
            float go = gates[3 * HD1 + m];
            c = fmaf(gf, c, gi * gg);
            float th = 2.f / (1.f + __expf(-2.f * c)) - 1.f;
            float h = go * th;
            float hn = __shfl_down(h, 1, 64);
            if ((m & 1) == 0) {
                ((unsigned int*)hp)[m >> 1] = packh(h, hn);
                size_t off = (((size_t)(t >> 4) * 64 + bg) * CH + (t & 15)) * LINE_H
                           + (m >> 3) * 128 + bt * 8 + (m & 7);
                *(unsigned int*)(h1relu + off) = packh(fmaxf(h, 0.f), fmaxf(hn, 0.f));
            }
        }
        __syncthreads();
    }
}

// ---------------------------------------------------------------------------
// Phase 2: LSTM layer 2 — MFMA, in-register gates, chunked h1, PINNED A-frags.
//
// R9 RATIONALE: R6/R7/R8 all showed VGPR_Count < 96 = size of a[4][6] alone
// (88 in R8) -> the "persistent" A-fragments were never resident. LLVM
// rematerialized the pure w2f loads JIT next to each MFMA: 24 L2-hit loads
// (~200cy each) serialized into the MFMA chain ≈ 4000 cy/step — exactly the
// observed per-step latency, and why R6->R8 structural fixes moved nothing.
// Fix: pin() each fragment (opaque "+v" asm) so rematerialization is
// illegal. Budget: 96(a)+24(bfr)+16(acc)+16(bs)+~30 misc ≈ 180 ≤ 256.
// ---------------------------------------------------------------------------
__global__ __launch_bounds__(512, 1)
void lstm2_kernel(const _Float16* __restrict__ h1relu,
                  const _Float16* __restrict__ w2f,
                  const float* __restrict__ b_ih2,
                  const float* __restrict__ b_hh2,
                  float* __restrict__ h2last)
{
    const int tid = threadIdx.x;
    const int l   = tid & 63;
    const int wv  = tid >> 6;              // 0..7
    const int bg  = blockIdx.x;            // batch group (16 batches)
    const int b0  = bg * NB2;
    const int bt  = l & 15;
    const int u0  = wv * 16 + ((l >> 4) << 2);
    const bool workerWave = (wv < 7);
    const bool worker = workerWave && (u0 < HD2);

    __shared__ _Float16 chunkbuf[2][CH * LINE_H];  // 2 x 40KB h1 chunks
    __shared__ _Float16 h2buf[2][H2G * 128];       // 2 x 3.5KB h2 frags

    // persistent A-fragments — loaded once, then PINNED resident
    const int wvc = workerWave ? wv : 6;
    f16x8 a[4][NKT];
#pragma unroll
    for (int g = 0; g < 4; g++)
#pragma unroll
        for (int kt = 0; kt < NKT; kt++) {
            a[g][kt] = *(const f16x8*)(w2f +
                ((size_t)((g * NUT + wvc) * NKT + kt) * 64 + l) * 8);
            pin(a[g][kt]);
        }

    float bs[4][4];
#pragma unroll
    for (int g = 0; g < 4; g++)
#pragma unroll
        for (int r = 0; r < 4; r++) {
            int uu = (u0 + r < HD2) ? (u0 + r) : 0;
            bs[g][r] = b_ih2[g * HD2 + uu] + b_hh2[g * HD2 + uu];
        }

    float c[4] = {0.f, 0.f, 0.f, 0.f};

    // zero h2 buffers (incl. pad groups) : 1792 dwords
    for (int i = tid; i < H2G * 128; i += 512) ((unsigned int*)h2buf)[i] = 0u;

    // prologue: DMA chunk 0 into chunkbuf[0]
    if (wv == 7) {
        const _Float16* g = h1relu + (size_t)bg * CH * LINE_H + l * 8;
#pragma unroll
        for (int i = 0; i < 40; i++)
            gld_lds16(g + i * 512, &chunkbuf[0][i * 512]);
    }
    __syncthreads();   // drains DMA + covers zeroing

    int cur = 0;
    for (int t = 0; t < T_STEPS; t++) {
        const int tc = t & (CH - 1);
        const int cb = (t >> 4) & 1;

        if (workerWave) {
            const _Float16* ck = &chunkbuf[cb][tc * LINE_H];
            f16x8 bfr[NKT];
#pragma unroll
            for (int kt = 0; kt < NKT; kt++) {
                int gi = kt * 4 + (l >> 4);
                const _Float16* src = (gi < 10)
                    ? (ck + gi * 128 + bt * 8)
                    : (&h2buf[cur][0] + (gi - 10) * 128 + bt * 8);
                bfr[kt] = *(const f16x8*)src;
            }

            f32x4 acc[4];
#pragma unroll
            for (int g = 0; g < 4; g++) {
                f32x4 z4 = {0.f, 0.f, 0.f, 0.f};
#pragma unroll
                for (int kt = 0; kt < NKT; kt++)
                    z4 = __builtin_amdgcn_mfma_f32_16x16x32_f16(
                             a[g][kt], bfr[kt], z4, 0, 0, 0);
                acc[g] = z4;
            }

            if (worker) {
                f16x4 hh;
#pragma unroll
                for (int r = 0; r < 4; r++) {
                    float zi = acc[0][r] + bs[0][r];
                    float zf = acc[1][r] + bs[1][r];
                    float zg = acc[2][r] + bs[2][r];
                    float zo = acc[3][r] + bs[3][r];
                    float gi = 1.f / (1.f + __expf(-zi));
                    float gf = 1.f / (1.f + __expf(-zf));
                    float gg = 2.f / (1.f + __expf(-2.f * zg)) - 1.f;
                    float go = 1.f / (1.f + __expf(-zo));
                    c[r] = fmaf(gf, c[r], gi * gg);
                    float th = 2.f / (1.f + __expf(-2.f * c[r])) - 1.f;
                    float h = go * th;
                    hh[r] = (_Float16)h;
                    if (t == T_STEPS - 1)
                        h2last[(size_t)(b0 + bt) * HD2 + u0 + r] = fmaxf(h, 0.f);
                }
                int k0 = HD1 + u0;             // k0&7 in {0,4}
                *(f16x4*)&h2buf[cur ^ 1][((k0 >> 3) - 10) * 128 + bt * 8 + (k0 & 7)] = hh;
            }
        } else {
            // stager wave: once per chunk, DMA next chunk (one drain/chunk)
            if (tc == 0 && (t >> 4) + 1 < NCH) {
                const _Float16* g = h1relu +
                    ((size_t)((t >> 4) + 1) * 64 + bg) * CH * LINE_H + l * 8;
                _Float16* dst = &chunkbuf[cb ^ 1][0];
#pragma unroll
                for (int i = 0; i < 40; i++)
                    gld_lds16(g + i * 512, dst + i * 512);
            }
        }
        __syncthreads();                       // single barrier per step
        cur ^= 1;
    }
}

// ---------------------------------------------------------------------------
// Head: out[b] = W_l2 @ relu(W_l1 @ h2last[b] + b_l1) + b_l2
// ---------------------------------------------------------------------------
__global__ __launch_bounds__(64)
void head_kernel(const float* __restrict__ h2last,
                 const float* __restrict__ W_l1,
                 const float* __restrict__ b_l1,
                 const float* __restrict__ W_l2,
                 const float* __restrict__ b_l2,
                 float* __restrict__ out)
{
    int b = blockIdx.x * 64 + threadIdx.x;
    if (b >= BATCH) return;
    const float* h = h2last + (size_t)b * HD2;
    float o = b_l2[0];
#pragma unroll
    for (int u = 0; u < 10; u++) {
        float s = b_l1[u];
#pragma unroll
        for (int k = 0; k < HD2; k++) s = fmaf(W_l1[u * HD2 + k], h[k], s);
        o = fmaf(W_l2[u], fmaxf(s, 0.f), o);
    }
    out[b] = o;
}

extern "C" void kernel_launch(void* const* d_in, const int* in_sizes, int n_in,
                              void* d_out, int out_size, void* d_ws, size_t ws_size,
                              hipStream_t stream)
{
    const float* x     = (const float*)d_in[0];
    const float* W_ih1 = (const float*)d_in[1];
    const float* W_hh1 = (const float*)d_in[2];
    const float* b_ih1 = (const float*)d_in[3];
    const float* b_hh1 = (const float*)d_in[4];
    const float* W_ih2 = (const float*)d_in[5];
    const float* W_hh2 = (const float*)d_in[6];
    const float* b_ih2 = (const float*)d_in[7];
    const float* b_hh2 = (const float*)d_in[8];
    const float* W_l1  = (const float*)d_in[9];
    const float* b_l1  = (const float*)d_in[10];
    const float* W_l2  = (const float*)d_in[11];
    const float* b_l2  = (const float*)d_in[12];
    float* out = (float*)d_out;

    // ws layout: h1relu f16 chunk-layout (84 MB) | h2last f32 | w1t | w2f
    char* p = (char*)d_ws;
    _Float16* h1relu = (_Float16*)p;           p += (size_t)T_STEPS * BATCH * HD1 * 2;
    float* h2last    = (float*)p;              p += (size_t)BATCH * HD2 * 4;
    unsigned int* w1t = (unsigned int*)p;      p += (size_t)W1_DW * NR1 * 4;
    unsigned int* w2fu = (unsigned int*)p;

    int prep_n = W1_DW * NR1 + W2F_DW;
    hipLaunchKernelGGL(prep_kernel, dim3((prep_n + 255) / 256), dim3(256), 0, stream,
                       W_hh1, W_ih2, W_hh2, w1t, w2fu);
    hipLaunchKernelGGL(lstm1_kernel, dim3(BATCH), dim3(NR1), 0, stream,
                       x, W_ih1, w1t, b_ih1, b_hh1, h1relu);
    hipLaunchKernelGGL(lstm2_kernel, dim3(BATCH / NB2), dim3(512), 0, stream,
                       h1relu, (const _Float16*)w2fu, b_ih2, b_hh2, h2last);
    hipLaunchKernelGGL(head_kernel, dim3(BATCH / 64), dim3(64), 0, stream,
                       h2last, W_l1, b_l1, W_l2, b_l2, out);
}

// Round 10
// 1314.133 us; speedup vs baseline: 1.0819x; 1.0771x over previous
//
#include <hip/hip_runtime.h>
#include <hip/hip_bf16.h>

#define T_STEPS 512
#define BATCH   1024
#define HD1     80
#define HD2     100
#define NB2     16                     // batches per block (MFMA N=16)

// ---- MFMA fragment geometry ----
// lstm1: K=96 (80 h1 + 16 pad), 3 k-tiles; 20 row-tiles (5 unit-tiles x 4 gates, exact)
// lstm2: K=192 (80 h1relu + 100 h2 + 12 pad), 6 k-tiles; 28 row-tiles (7 x 4, units padded 100->112)
#define NKT1    3
#define NUT1    5
#define NT1     (4 * NUT1)             // 20
#define NKT2    6
#define NUT2    7
#define NT2     (4 * NUT2)             // 28
#define W1F_DW  (NT1 * NKT1 * 64 * 4)  // 15360 dwords of lstm1 A-fragments
#define W2F_DW  (NT2 * NKT2 * 64 * 4)  // 43008 dwords of lstm2 A-fragments

typedef _Float16 half2_t __attribute__((ext_vector_type(2)));
typedef _Float16 f16x4   __attribute__((ext_vector_type(4)));
typedef _Float16 f16x8   __attribute__((ext_vector_type(8)));
typedef float    f32x4   __attribute__((ext_vector_type(4)));

union HU { unsigned int u; half2_t h; };
static __device__ __forceinline__ unsigned int packh(float a, float b) {
    HU x; x.h.x = (_Float16)a; x.h.y = (_Float16)b; return x.u;
}

// ---------------------------------------------------------------------------
// Prep: pack BOTH layers' weights as MFMA A-fragments.
// Gauge (same k-map as the in-kernel B-pack, R6/R9-verified):
//   half F = ((tile*NKT + kt)*64 + lane)*8 + s  holds  Wrow[row(tile,lane)][k]
//   with k = kt*32 + (lane>>4)*8 + s.
// lstm1: tile = g*5 + j, row r = g*80 + j*16 + (lane&15); k<80 -> W_hh1[r][k].
// lstm2: tile = g*7 + j, unit up = j*16 + (lane&15) (pad >=100 -> 0);
//        k<80 -> W_ih2[r][k]; k<180 -> W_hh2[r][k-80]; else 0  (r=g*100+up).
// ---------------------------------------------------------------------------
__global__ __launch_bounds__(256)
void prep_kernel(const float* __restrict__ W_hh1,
                 const float* __restrict__ W_ih2,
                 const float* __restrict__ W_hh2,
                 unsigned int* __restrict__ w1f,
                 unsigned int* __restrict__ w2f)
{
    int i = blockIdx.x * 256 + threadIdx.x;
    if (i < W1F_DW) {
        int H  = 2 * i;
        int s  = H & 7;
        int l  = (H >> 3) & 63;
        int ri = H >> 9;                       // tile*NKT1 + kt
        int kt = ri % NKT1;
        int tile = ri / NKT1;                  // 0..19
        int g  = tile / NUT1, j = tile % NUT1;
        int r  = g * HD1 + j * 16 + (l & 15);
        int k  = kt * 32 + (l >> 4) * 8 + s;
        float v0 = (k     < HD1) ? W_hh1[r * HD1 + k]     : 0.f;
        float v1 = (k + 1 < HD1) ? W_hh1[r * HD1 + k + 1] : 0.f;
        w1f[i] = packh(v0, v1);
    } else if (i < W1F_DW + W2F_DW) {
        int d  = i - W1F_DW;
        int H  = 2 * d;
        int s  = H & 7;
        int l  = (H >> 3) & 63;
        int ri = H >> 9;                       // tile*NKT2 + kt
        int kt = ri % NKT2;
        int tile = ri / NKT2;                  // 0..27
        int g  = tile / NUT2, j = tile % NUT2;
        int up = j * 16 + (l & 15);
        int k  = kt * 32 + (l >> 4) * 8 + s;
        float v0 = 0.f, v1 = 0.f;
        if (up < HD2) {
            int r = g * HD2 + up;
            v0 = (k < HD1) ? W_ih2[r * HD1 + k]
               : (k < HD1 + HD2) ? W_hh2[r * HD2 + (k - HD1)] : 0.f;
            int k1 = k + 1;
            v1 = (k1 < HD1) ? W_ih2[r * HD1 + k1]
               : (k1 < HD1 + HD2) ? W_hh2[r * HD2 + (k1 - HD1)] : 0.f;
        }
        w2f[d] = packh(v0, v1);
    }
}

// ---------------------------------------------------------------------------
// FUSED two-layer LSTM. 64 blocks x 768 threads (12 waves), 16 batches/block.
//
// R10 RATIONALE: VALUBusy/MfmaUtil are CHIP-normalized; with 64 blocks only
// 64/256 CUs are active -> R9's 16.4% VALUBusy = ~66% on active CUs. lstm2
// is VALU-THROUGHPUT-bound on a quarter of the chip (why R6-R9 structural
// changes all landed ~850-910us: none changed per-CU VALU work). The h2
// recurrence caps blocks at 64, so the win is packing MORE work per block:
// fuse lstm1 (same MFMA+in-reg-gate structure, K=96) as a second wave role,
// software-pipelined one step behind:
//   iter i: waves 7..11 compute h1(i) (raw->h1b, relu->h1r);
//           waves 0..6  compute h2(i-1) from h1r(i-1) + h2(i-2).
// One barrier per iter; 513 iters. x(t) term added exactly in f32 in the
// gate phase (x never quantized through MFMA). h1relu NEVER touches global:
// the 84MB workspace round-trip and the whole lstm1 kernel disappear.
// Parity: buf[p] holds step s=p&1 state; reads/writes alternate (derived in
// journal; zero both parities at init so step -1 reads are 0).
// ---------------------------------------------------------------------------
__global__ __launch_bounds__(768, 1)
void lstm_fused(const float* __restrict__ x,
                const float* __restrict__ W_ih1,
                const _Float16* __restrict__ w1f,
                const float* __restrict__ b_ih1,
                const float* __restrict__ b_hh1,
                const _Float16* __restrict__ w2f,
                const float* __restrict__ b_ih2,
                const float* __restrict__ b_hh2,
                float* __restrict__ h2last)
{
    const int tid = threadIdx.x;
    const int l   = tid & 63;
    const int wv  = tid >> 6;              // 0..11
    const int b0  = blockIdx.x * NB2;
    const int bt  = l & 15;                // batch column (C/D col = lane&15)
    const int ro  = (l >> 4) << 2;         // unit offset  (C/D row = (lane>>4)*4+reg)
    const bool isL2 = (wv < 7);

    __shared__ float    xs[T_STEPS * NB2];        // 32KB: x[t][bt] f32 (exact)
    __shared__ _Float16 h1b[2][12 * 128];         // raw h1, K=96 B-layout (grp 10,11 = 0)
    __shared__ _Float16 h1r[2][10 * 128];         // relu(h1) for lstm2 (k=0..79)
    __shared__ _Float16 h2b[2][14 * 128];         // h2 region k=80..191 (pad zeroed)

    // ---- persistent A-fragments (role-dependent; unified array) ----
    f16x8 a[4][NKT2];
    if (isL2) {
#pragma unroll
        for (int g = 0; g < 4; g++)
#pragma unroll
            for (int kt = 0; kt < NKT2; kt++)
                a[g][kt] = *(const f16x8*)(w2f +
                    ((size_t)((g * NUT2 + wv) * NKT2 + kt) * 64 + l) * 8);
    } else {
        const int j1 = wv - 7;             // 0..4
#pragma unroll
        for (int g = 0; g < 4; g++)
#pragma unroll
            for (int kt = 0; kt < NKT1; kt++)
                a[g][kt] = *(const f16x8*)(w1f +
                    ((size_t)((g * NUT1 + j1) * NKT1 + kt) * 64 + l) * 8);
    }

    // ---- per-lane gate constants ----
    const int u0 = isL2 ? (wv * 16 + ro) : ((wv - 7) * 16 + ro);
    const bool worker = isL2 ? (u0 < HD2) : true;   // lstm1 units exact (u0<80)
    float bs[4][4], w1x[4][4];
#pragma unroll
    for (int g = 0; g < 4; g++)
#pragma unroll
        for (int r = 0; r < 4; r++) {
            if (isL2) {
                int uu = (u0 + r < HD2) ? (u0 + r) : 0;
                bs[g][r] = b_ih2[g * HD2 + uu] + b_hh2[g * HD2 + uu];
                w1x[g][r] = 0.f;
            } else {
                int j = g * HD1 + u0 + r;
                bs[g][r] = b_ih1[j] + b_hh1[j];
                w1x[g][r] = W_ih1[j];
            }
        }

    float c[4] = {0.f, 0.f, 0.f, 0.f};

    // ---- init LDS: zero state bufs (both parities), load x chunk ----
    for (int i = tid; i < 2 * 12 * 128 / 2; i += 768) ((unsigned int*)h1b)[i] = 0u;
    for (int i = tid; i < 2 * 10 * 128 / 2; i += 768) ((unsigned int*)h1r)[i] = 0u;
    for (int i = tid; i < 2 * 14 * 128 / 2; i += 768) ((unsigned int*)h2b)[i] = 0u;
    for (int idx = tid; idx < T_STEPS * NB2; idx += 768) {
        int tt = idx & (T_STEPS - 1), bb = idx >> 9;   // coalesced global read
        xs[tt * NB2 + bb] = x[((size_t)(b0 + bb)) * T_STEPS + tt];
    }
    __syncthreads();

    for (int i = 0; i <= T_STEPS; i++) {
        if (isL2) {
            if (i >= 1) {
                // B-frags: h1relu(i-1) (groups 0..9) + h2(i-2) (groups 10..23)
                const _Float16* h1p = h1r[(i - 1) & 1];
                const _Float16* h2p = h2b[i & 1];
                f16x8 bfr[NKT2];
#pragma unroll
                for (int kt = 0; kt < NKT2; kt++) {
                    int gi = kt * 4 + (l >> 4);
                    const _Float16* src = (gi < 10)
                        ? (h1p + gi * 128 + bt * 8)
                        : (h2p + (gi - 10) * 128 + bt * 8);
                    bfr[kt] = *(const f16x8*)src;
                }
                f32x4 acc[4];
#pragma unroll
                for (int g = 0; g < 4; g++) {
                    f32x4 z4 = {0.f, 0.f, 0.f, 0.f};
#pragma unroll
                    for (int kt = 0; kt < NKT2; kt++)
                        z4 = __builtin_amdgcn_mfma_f32_16x16x32_f16(
                                 a[g][kt], bfr[kt], z4, 0, 0, 0);
                    acc[g] = z4;
                }
                if (worker) {
                    f16x4 hh;
#pragma unroll
                    for (int r = 0; r < 4; r++) {
                        float zi = acc[0][r] + bs[0][r];
                        float zf = acc[1][r] + bs[1][r];
                        float zg = acc[2][r] + bs[2][r];
                        float zo = acc[3][r] + bs[3][r];
                        float gi = 1.f / (1.f + __expf(-zi));
                        float gf = 1.f / (1.f + __expf(-zf));
                        float gg = 2.f / (1.f + __expf(-2.f * zg)) - 1.f;
                        float go = 1.f / (1.f + __expf(-zo));
                        c[r] = fmaf(gf, c[r], gi * gg);
                        float th = 2.f / (1.f + __expf(-2.f * c[r])) - 1.f;
                        float h = go * th;
                        hh[r] = (_Float16)h;
                        if (i == T_STEPS)
                            h2last[(size_t)(b0 + bt) * HD2 + u0 + r] = fmaxf(h, 0.f);
                    }
                    int k0 = HD1 + u0;     // k=80..179; k0&7 in {0,4}
                    *(f16x4*)&h2b[(i + 1) & 1]
                        [((k0 >> 3) - 10) * 128 + bt * 8 + (k0 & 7)] = hh;
                }
            }
        } else {
            if (i < T_STEPS) {
                // B-frags: raw h1(i-1), K=96 (groups 10,11 permanent zeros)
                const _Float16* hbp = h1b[(i + 1) & 1];
                f16x8 bfr[NKT1];
#pragma unroll
                for (int kt = 0; kt < NKT1; kt++) {
                    int gi = kt * 4 + (l >> 4);
                    bfr[kt] = *(const f16x8*)(hbp + gi * 128 + bt * 8);
                }
                f32x4 acc[4];
#pragma unroll
                for (int g = 0; g < 4; g++) {
                    f32x4 z4 = {0.f, 0.f, 0.f, 0.f};
#pragma unroll
                    for (int kt = 0; kt < NKT1; kt++)
                        z4 = __builtin_amdgcn_mfma_f32_16x16x32_f16(
                                 a[g][kt], bfr[kt], z4, 0, 0, 0);
                    acc[g] = z4;
                }
                float xf = xs[i * NB2 + bt];   // exact f32 x-term
                f16x4 hraw, hrel;
#pragma unroll
                for (int r = 0; r < 4; r++) {
                    float zi = acc[0][r] + bs[0][r] + w1x[0][r] * xf;
                    float zf = acc[1][r] + bs[1][r] + w1x[1][r] * xf;
                    float zg = acc[2][r] + bs[2][r] + w1x[2][r] * xf;
                    float zo = acc[3][r] + bs[3][r] + w1x[3][r] * xf;
                    float gi = 1.f / (1.f + __expf(-zi));
                    float gf = 1.f / (1.f + __expf(-zf));
                    float gg = 2.f / (1.f + __expf(-2.f * zg)) - 1.f;
                    float go = 1.f / (1.f + __expf(-zo));
                    c[r] = fmaf(gf, c[r], gi * gg);
                    float th = 2.f / (1.f + __expf(-2.f * c[r])) - 1.f;
                    float h = go * th;
                    hraw[r] = (_Float16)h;
                    hrel[r] = (_Float16)fmaxf(h, 0.f);
                }
                int off = (u0 >> 3) * 128 + bt * 8 + (u0 & 7);   // u0&7 in {0,4}
                *(f16x4*)&h1b[i & 1][off] = hraw;
                *(f16x4*)&h1r[i & 1][off] = hrel;
            }
        }
        __syncthreads();                       // single barrier per iter
    }
}

// ---------------------------------------------------------------------------
// Head: out[b] = W_l2 @ relu(W_l1 @ h2last[b] + b_l1) + b_l2
// ---------------------------------------------------------------------------
__global__ __launch_bounds__(64)
void head_kernel(const float* __restrict__ h2last,
                 const float* __restrict__ W_l1,
                 const float* __restrict__ b_l1,
                 const float* __restrict__ W_l2,
                 const float* __restrict__ b_l2,
                 float* __restrict__ out)
{
    int b = blockIdx.x * 64 + threadIdx.x;
    if (b >= BATCH) return;
    const float* h = h2last + (size_t)b * HD2;
    float o = b_l2[0];
#pragma unroll
    for (int u = 0; u < 10; u++) {
        float s = b_l1[u];
#pragma unroll
        for (int k = 0; k < HD2; k++) s = fmaf(W_l1[u * HD2 + k], h[k], s);
        o = fmaf(W_l2[u], fmaxf(s, 0.f), o);
    }
    out[b] = o;
}

extern "C" void kernel_launch(void* const* d_in, const int* in_sizes, int n_in,
                              void* d_out, int out_size, void* d_ws, size_t ws_size,
                              hipStream_t stream)
{
    const float* x     = (const float*)d_in[0];
    const float* W_ih1 = (const float*)d_in[1];
    const float* W_hh1 = (const float*)d_in[2];
    const float* b_ih1 = (const float*)d_in[3];
    const float* b_hh1 = (const float*)d_in[4];
    const float* W_ih2 = (const float*)d_in[5];
    const float* W_hh2 = (const float*)d_in[6];
    const float* b_ih2 = (const float*)d_in[7];
    const float* b_hh2 = (const float*)d_in[8];
    const float* W_l1  = (const float*)d_in[9];
    const float* b_l1  = (const float*)d_in[10];
    const float* W_l2  = (const float*)d_in[11];
    const float* b_l2  = (const float*)d_in[12];
    float* out = (float*)d_out;

    // ws layout: h2last f32 | w1f | w2f   (h1relu workspace eliminated)
    char* p = (char*)d_ws;
    float* h2last      = (float*)p;        p += (size_t)BATCH * HD2 * 4;
    unsigned int* w1fu = (unsigned int*)p; p += (size_t)W1F_DW * 4;
    unsigned int* w2fu = (unsigned int*)p;

    int prep_n = W1F_DW + W2F_DW;
    hipLaunchKernelGGL(prep_kernel, dim3((prep_n + 255) / 256), dim3(256), 0, stream,
                       W_hh1, W_ih2, W_hh2, w1fu, w2fu);
    hipLaunchKernelGGL(lstm_fused, dim3(BATCH / NB2), dim3(768), 0, stream,
                       x, W_ih1, (const _Float16*)w1fu, b_ih1, b_hh1,
                       (const _Float16*)w2fu, b_ih2, b_hh2, h2last);
    hipLaunchKernelGGL(head_kernel, dim3(BATCH / 64), dim3(64), 0, stream,
                       h2last, W_l1, b_l1, W_l2, b_l2, out);
}

// Round 11
// 1252.886 us; speedup vs baseline: 1.1348x; 1.0489x over previous
//
#include <hip/hip_runtime.h>
#include <hip/hip_bf16.h>

#define T_STEPS 512
#define BATCH   1024
#define HD1     80
#define HD2     100
#define NB2     16                     // batches per block (MFMA N=16)

// ---- MFMA fragment geometry ----
// lstm1: K=96 (80 h1 + bias@80 + W_ih1@81 + pad), 3 k-tiles; 20 row-tiles
// lstm2: K=192 (80 h1relu + 100 h2 + bias@180 + pad), 6 k-tiles; 28 row-tiles
#define NKT1    3
#define NUT1    5
#define NT1     (4 * NUT1)             // 20
#define NKT2    6
#define NUT2    7
#define NT2     (4 * NUT2)             // 28
#define W1F_DW  (NT1 * NKT1 * 64 * 4)  // 15360 dwords of lstm1 A-fragments
#define W2F_DW  (NT2 * NKT2 * 64 * 4)  // 43008 dwords of lstm2 A-fragments

typedef _Float16 half2_t __attribute__((ext_vector_type(2)));
typedef _Float16 f16x4   __attribute__((ext_vector_type(4)));
typedef _Float16 f16x8   __attribute__((ext_vector_type(8)));
typedef float    f32x4   __attribute__((ext_vector_type(4)));

union HU { unsigned int u; half2_t h; };
static __device__ __forceinline__ unsigned int packh(float a, float b) {
    HU x; x.h.x = (_Float16)a; x.h.y = (_Float16)b; return x.u;
}

// ---------------------------------------------------------------------------
// Prep: pack BOTH layers' weights as MFMA A-fragments, WITH bias/x folded
// into the K-padding (R11):
// lstm1 row r (tile g*5+j, r = g*80 + j*16 + (lane&15)):
//   k<80 -> W_hh1[r][k]; k==80 -> b_ih1[r]+b_hh1[r]; k==81 -> W_ih1[r]; else 0
// lstm2 row (tile g*7+j, up = j*16+(lane&15), pad up>=100 -> 0; r = g*100+up):
//   k<80 -> W_ih2[r][k]; k<180 -> W_hh2[r][k-80];
//   k==180 -> b_ih2[r]+b_hh2[r]; else 0
// B-side carries 1.0 at k=80 (lstm1) / k=180 (lstm2), and x(t) at k=81.
// ---------------------------------------------------------------------------
__global__ __launch_bounds__(256)
void prep_kernel(const float* __restrict__ W_hh1,
                 const float* __restrict__ W_ih2,
                 const float* __restrict__ W_hh2,
                 const float* __restrict__ W_ih1,
                 const float* __restrict__ b_ih1,
                 const float* __restrict__ b_hh1,
                 const float* __restrict__ b_ih2,
                 const float* __restrict__ b_hh2,
                 unsigned int* __restrict__ w1f,
                 unsigned int* __restrict__ w2f)
{
    int i = blockIdx.x * 256 + threadIdx.x;
    if (i < W1F_DW) {
        int H  = 2 * i;
        int s  = H & 7;
        int l  = (H >> 3) & 63;
        int ri = H >> 9;                       // tile*NKT1 + kt
        int kt = ri % NKT1;
        int tile = ri / NKT1;                  // 0..19
        int g  = tile / NUT1, j = tile % NUT1;
        int r  = g * HD1 + j * 16 + (l & 15);
        int k  = kt * 32 + (l >> 4) * 8 + s;
        auto val1 = [&](int kk) -> float {
            if (kk < HD1) return W_hh1[r * HD1 + kk];
            if (kk == HD1) return b_ih1[r] + b_hh1[r];
            if (kk == HD1 + 1) return W_ih1[r];
            return 0.f;
        };
        w1f[i] = packh(val1(k), val1(k + 1));
    } else if (i < W1F_DW + W2F_DW) {
        int d  = i - W1F_DW;
        int H  = 2 * d;
        int s  = H & 7;
        int l  = (H >> 3) & 63;
        int ri = H >> 9;                       // tile*NKT2 + kt
        int kt = ri % NKT2;
        int tile = ri / NKT2;                  // 0..27
        int g  = tile / NUT2, j = tile % NUT2;
        int up = j * 16 + (l & 15);
        int k  = kt * 32 + (l >> 4) * 8 + s;
        float v0 = 0.f, v1 = 0.f;
        if (up < HD2) {
            int r = g * HD2 + up;
            auto val2 = [&](int kk) -> float {
                if (kk < HD1) return W_ih2[r * HD1 + kk];
                if (kk < HD1 + HD2) return W_hh2[r * HD2 + (kk - HD1)];
                if (kk == HD1 + HD2) return b_ih2[r] + b_hh2[r];
                return 0.f;
            };
            v0 = val2(k); v1 = val2(k + 1);
        }
        w2f[d] = packh(v0, v1);
    }
}

// ---------------------------------------------------------------------------
// FUSED two-layer LSTM. 64 blocks x 768 threads (12 waves), 16 batches/block.
//
// R11 RATIONALE: R10's VGPR_Count=84 < 96 = a[4][6] alone -> A-fragments
// STILL rematerialized from L2 every iter (invisible in FETCH: w2f is
// L2-resident). R9's pin() produced bit-identical codegen (same VGPR/dur),
// so it never took; that null didn't falsify residency. Per-iter latency
// 5850cy vs ~1800cy busy leaves ~3500cy idle = serialized L2 weight reloads.
// Fixes: (1) VOLATILE a-loads — cannot be re-executed, values must stay
// live; (2) register diet to fit the 170-cap of 12 resident waves: fold
// bias into MFMA K-pad (A: bias@k=180/k=80; B: 1.0 there) and the lstm1
// x-term likewise (A: W_ih1@k=81; B: x(t) f16, written one iter ahead
// during the gate phase). Kills bs[16]+w1x[16] regs + 32 adds/iter.
// L2 pressure: 96a+24bfr+16acc+4c+~15misc = 155 <= 170.
// Pipeline unchanged: iter i = L1 computes h1(i) || L2 computes h2(i-1).
// ---------------------------------------------------------------------------
__global__ __launch_bounds__(768, 1)
void lstm_fused(const float* __restrict__ x,
                const _Float16* __restrict__ w1f,
                const _Float16* __restrict__ w2f,
                float* __restrict__ h2last)
{
    const int tid = threadIdx.x;
    const int l   = tid & 63;
    const int wv  = tid >> 6;              // 0..11
    const int b0  = blockIdx.x * NB2;
    const int bt  = l & 15;                // batch column (C/D col = lane&15)
    const int ro  = (l >> 4) << 2;         // unit offset  (C/D row = (lane>>4)*4+reg)
    const bool isL2 = (wv < 7);

    __shared__ float    xs[T_STEPS * NB2];        // 32KB: x[t][bt] f32
    __shared__ _Float16 h1b[2][12 * 128];         // raw h1 + 1.0/x slots, K=96 B-layout
    __shared__ _Float16 h1r[2][10 * 128];         // relu(h1) for lstm2 (k=0..79)
    __shared__ _Float16 h2b[2][14 * 128];         // h2 region k=80..191 (+1.0 slot)

    // ---- persistent A-fragments: VOLATILE loads -> cannot be remat'd ----
    f16x8 a[4][NKT2];
    if (isL2) {
#pragma unroll
        for (int g = 0; g < 4; g++)
#pragma unroll
            for (int kt = 0; kt < NKT2; kt++)
                a[g][kt] = *(const volatile f16x8*)(w2f +
                    ((size_t)((g * NUT2 + wv) * NKT2 + kt) * 64 + l) * 8);
    } else {
        const int j1 = wv - 7;             // 0..4
#pragma unroll
        for (int g = 0; g < 4; g++)
#pragma unroll
            for (int kt = 0; kt < NKT1; kt++)
                a[g][kt] = *(const volatile f16x8*)(w1f +
                    ((size_t)((g * NUT1 + j1) * NKT1 + kt) * 64 + l) * 8);
    }

    const int u0 = isL2 ? (wv * 16 + ro) : ((wv - 7) * 16 + ro);
    const bool worker = isL2 ? (u0 < HD2) : true;

    float c[4] = {0.f, 0.f, 0.f, 0.f};

    // ---- init LDS: zero state bufs, load x, set 1.0/x(0) special slots ----
    for (int i = tid; i < 2 * 12 * 128 / 2; i += 768) ((unsigned int*)h1b)[i] = 0u;
    for (int i = tid; i < 2 * 10 * 128 / 2; i += 768) ((unsigned int*)h1r)[i] = 0u;
    for (int i = tid; i < 2 * 14 * 128 / 2; i += 768) ((unsigned int*)h2b)[i] = 0u;
    for (int idx = tid; idx < T_STEPS * NB2; idx += 768) {
        int tt = idx & (T_STEPS - 1), bb = idx >> 9;
        xs[tt * NB2 + bb] = x[((size_t)(b0 + bb)) * T_STEPS + tt];
    }
    __syncthreads();
    if (tid < NB2) {
        h1b[0][10 * 128 + tid * 8 + 0] = (_Float16)1.f;   // k=80: 1.0 (bias)
        h1b[1][10 * 128 + tid * 8 + 0] = (_Float16)1.f;
        h1b[1][10 * 128 + tid * 8 + 1] =                   // k=81: x(0) for i=0
            (_Float16)x[((size_t)(b0 + tid)) * T_STEPS];
        h2b[0][12 * 128 + tid * 8 + 4] = (_Float16)1.f;   // k=180: 1.0 (bias)
        h2b[1][12 * 128 + tid * 8 + 4] = (_Float16)1.f;
    }
    __syncthreads();

    for (int i = 0; i <= T_STEPS; i++) {
        if (isL2) {
            if (i >= 1) {
                const _Float16* h1p = h1r[(i - 1) & 1];
                const _Float16* h2p = h2b[i & 1];
                f16x8 bfr[NKT2];
#pragma unroll
                for (int kt = 0; kt < NKT2; kt++) {
                    int gi = kt * 4 + (l >> 4);
                    const _Float16* src = (gi < 10)
                        ? (h1p + gi * 128 + bt * 8)
                        : (h2p + (gi - 10) * 128 + bt * 8);
                    bfr[kt] = *(const f16x8*)src;
                }
                f32x4 acc[4];
#pragma unroll
                for (int g = 0; g < 4; g++) {
                    f32x4 z4 = {0.f, 0.f, 0.f, 0.f};
#pragma unroll
                    for (int kt = 0; kt < NKT2; kt++)
                        z4 = __builtin_amdgcn_mfma_f32_16x16x32_f16(
                                 a[g][kt], bfr[kt], z4, 0, 0, 0);
                    acc[g] = z4;
                }
                if (worker) {
                    f16x4 hh;
#pragma unroll
                    for (int r = 0; r < 4; r++) {
                        float gi = 1.f / (1.f + __expf(-acc[0][r]));
                        float gf = 1.f / (1.f + __expf(-acc[1][r]));
                        float gg = 2.f / (1.f + __expf(-2.f * acc[2][r])) - 1.f;
                        float go = 1.f / (1.f + __expf(-acc[3][r]));
                        c[r] = fmaf(gf, c[r], gi * gg);
                        float th = 2.f / (1.f + __expf(-2.f * c[r])) - 1.f;
                        float h = go * th;
                        hh[r] = (_Float16)h;
                        if (i == T_STEPS)
                            h2last[(size_t)(b0 + bt) * HD2 + u0 + r] = fmaxf(h, 0.f);
                    }
                    int k0 = HD1 + u0;     // k=80..179; k0&7 in {0,4}
                    *(f16x4*)&h2b[(i + 1) & 1]
                        [((k0 >> 3) - 10) * 128 + bt * 8 + (k0 & 7)] = hh;
                }
            }
        } else {
            if (i < T_STEPS) {
                const _Float16* hbp = h1b[(i + 1) & 1];
                f16x8 bfr[NKT1];
#pragma unroll
                for (int kt = 0; kt < NKT1; kt++) {
                    int gi = kt * 4 + (l >> 4);
                    bfr[kt] = *(const f16x8*)(hbp + gi * 128 + bt * 8);
                }
                f32x4 acc[4];
#pragma unroll
                for (int g = 0; g < 4; g++) {
                    f32x4 z4 = {0.f, 0.f, 0.f, 0.f};
#pragma unroll
                    for (int kt = 0; kt < NKT1; kt++)
                        z4 = __builtin_amdgcn_mfma_f32_16x16x32_f16(
                                 a[g][kt], bfr[kt], z4, 0, 0, 0);
                    acc[g] = z4;
                }
                f16x4 hraw, hrel;
#pragma unroll
                for (int r = 0; r < 4; r++) {
                    float gi = 1.f / (1.f + __expf(-acc[0][r]));
                    float gf = 1.f / (1.f + __expf(-acc[1][r]));
                    float gg = 2.f / (1.f + __expf(-2.f * acc[2][r])) - 1.f;
                    float go = 1.f / (1.f + __expf(-acc[3][r]));
                    c[r] = fmaf(gf, c[r], gi * gg);
                    float th = 2.f / (1.f + __expf(-2.f * c[r])) - 1.f;
                    float h = go * th;
                    hraw[r] = (_Float16)h;
                    hrel[r] = (_Float16)fmaxf(h, 0.f);
                }
                int off = (u0 >> 3) * 128 + bt * 8 + (u0 & 7);
                *(f16x4*)&h1b[i & 1][off] = hraw;
                *(f16x4*)&h1r[i & 1][off] = hrel;
                // write x(i+1) into the K=81 slot of the buffer L1 reads next iter
                if (wv == 7 && l < NB2 && i + 1 < T_STEPS)
                    h1b[i & 1][10 * 128 + l * 8 + 1] =
                        (_Float16)xs[(i + 1) * NB2 + l];
            }
        }
        __syncthreads();                       // single barrier per iter
    }
}

// ---------------------------------------------------------------------------
// Head: out[b] = W_l2 @ relu(W_l1 @ h2last[b] + b_l1) + b_l2
// ---------------------------------------------------------------------------
__global__ __launch_bounds__(64)
void head_kernel(const float* __restrict__ h2last,
                 const float* __restrict__ W_l1,
                 const float* __restrict__ b_l1,
                 const float* __restrict__ W_l2,
                 const float* __restrict__ b_l2,
                 float* __restrict__ out)
{
    int b = blockIdx.x * 64 + threadIdx.x;
    if (b >= BATCH) return;
    const float* h = h2last + (size_t)b * HD2;
    float o = b_l2[0];
#pragma unroll
    for (int u = 0; u < 10; u++) {
        float s = b_l1[u];
#pragma unroll
        for (int k = 0; k < HD2; k++) s = fmaf(W_l1[u * HD2 + k], h[k], s);
        o = fmaf(W_l2[u], fmaxf(s, 0.f), o);
    }
    out[b] = o;
}

extern "C" void kernel_launch(void* const* d_in, const int* in_sizes, int n_in,
                              void* d_out, int out_size, void* d_ws, size_t ws_size,
                              hipStream_t stream)
{
    const float* x     = (const float*)d_in[0];
    const float* W_ih1 = (const float*)d_in[1];
    const float* W_hh1 = (const float*)d_in[2];
    const float* b_ih1 = (const float*)d_in[3];
    const float* b_hh1 = (const float*)d_in[4];
    const float* W_ih2 = (const float*)d_in[5];
    const float* W_hh2 = (const float*)d_in[6];
    const float* b_ih2 = (const float*)d_in[7];
    const float* b_hh2 = (const float*)d_in[8];
    const float* W_l1  = (const float*)d_in[9];
    const float* b_l1  = (const float*)d_in[10];
    const float* W_l2  = (const float*)d_in[11];
    const float* b_l2  = (const float*)d_in[12];
    float* out = (float*)d_out;

    // ws layout: h2last f32 | w1f | w2f
    char* p = (char*)d_ws;
    float* h2last      = (float*)p;        p += (size_t)BATCH * HD2 * 4;
    unsigned int* w1fu = (unsigned int*)p; p += (size_t)W1F_DW * 4;
    unsigned int* w2fu = (unsigned int*)p;

    int prep_n = W1F_DW + W2F_DW;
    hipLaunchKernelGGL(prep_kernel, dim3((prep_n + 255) / 256), dim3(256), 0, stream,
                       W_hh1, W_ih2, W_hh2, W_ih1, b_ih1, b_hh1, b_ih2, b_hh2,
                       w1fu, w2fu);
    hipLaunchKernelGGL(lstm_fused, dim3(BATCH / NB2), dim3(768), 0, stream,
                       x, (const _Float16*)w1fu, (const _Float16*)w2fu, h2last);
    hipLaunchKernelGGL(head_kernel, dim3(BATCH / 64), dim3(64), 0, stream,
                       h2last, W_l1, b_l1, W_l2, b_l2, out);
}

// Round 12
// 681.228 us; speedup vs baseline: 2.0870x; 1.8392x over previous
//
#include <hip/hip_runtime.h>
#include <hip/hip_bf16.h>

#define T_STEPS 512
#define BATCH   1024
#define HD1     80
#define HD2     100
#define NB2     16                     // batches per block (MFMA N=16)

// ---- MFMA fragment geometry ----
// lstm1: K=96 (80 h1 + bias@80 + W_ih1@81 + pad), 3 k-tiles; 20 row-tiles
// lstm2: K=192 (80 h1relu + 100 h2 + bias@180 + pad), 6 k-tiles; 28 row-tiles
#define NKT1    3
#define NUT1    5
#define NT1     (4 * NUT1)             // 20
#define NKT2    6
#define NUT2    7
#define NT2     (4 * NUT2)             // 28
#define W1F_DW  (NT1 * NKT1 * 64 * 4)  // 15360 dwords of lstm1 A-fragments
#define W2F_DW  (NT2 * NKT2 * 64 * 4)  // 43008 dwords of lstm2 A-fragments

typedef _Float16 half2_t __attribute__((ext_vector_type(2)));
typedef _Float16 f16x4   __attribute__((ext_vector_type(4)));
typedef _Float16 f16x8   __attribute__((ext_vector_type(8)));
typedef float    f32x4   __attribute__((ext_vector_type(4)));

union HU { unsigned int u; half2_t h; };
static __device__ __forceinline__ unsigned int packh(float a, float b) {
    HU x; x.h.x = (_Float16)a; x.h.y = (_Float16)b; return x.u;
}

// R12: 1-op reciprocal (v_rcp_f32, ~1ulp) — the compiled 1.f/x full-precision
// div sequence (div_scale+rcp+div_fmas+div_fixup ~10 ops) was the single
// largest VALU consumer (20 sigmoids/wave/iter).
static __device__ __forceinline__ float sigm(float z) {
    return __builtin_amdgcn_rcpf(1.f + __expf(-z));
}
static __device__ __forceinline__ float tanhf_(float z) {   // 2*sigm(2z)-1
    return fmaf(2.f, __builtin_amdgcn_rcpf(1.f + __expf(-2.f * z)), -1.f);
}

// ---------------------------------------------------------------------------
// Prep (unchanged from R11): A-fragments with bias/x folded into K-padding.
// ---------------------------------------------------------------------------
__global__ __launch_bounds__(256)
void prep_kernel(const float* __restrict__ W_hh1,
                 const float* __restrict__ W_ih2,
                 const float* __restrict__ W_hh2,
                 const float* __restrict__ W_ih1,
                 const float* __restrict__ b_ih1,
                 const float* __restrict__ b_hh1,
                 const float* __restrict__ b_ih2,
                 const float* __restrict__ b_hh2,
                 unsigned int* __restrict__ w1f,
                 unsigned int* __restrict__ w2f)
{
    int i = blockIdx.x * 256 + threadIdx.x;
    if (i < W1F_DW) {
        int H  = 2 * i;
        int s  = H & 7;
        int l  = (H >> 3) & 63;
        int ri = H >> 9;                       // tile*NKT1 + kt
        int kt = ri % NKT1;
        int tile = ri / NKT1;                  // 0..19
        int g  = tile / NUT1, j = tile % NUT1;
        int r  = g * HD1 + j * 16 + (l & 15);
        int k  = kt * 32 + (l >> 4) * 8 + s;
        auto val1 = [&](int kk) -> float {
            if (kk < HD1) return W_hh1[r * HD1 + kk];
            if (kk == HD1) return b_ih1[r] + b_hh1[r];
            if (kk == HD1 + 1) return W_ih1[r];
            return 0.f;
        };
        w1f[i] = packh(val1(k), val1(k + 1));
    } else if (i < W1F_DW + W2F_DW) {
        int d  = i - W1F_DW;
        int H  = 2 * d;
        int s  = H & 7;
        int l  = (H >> 3) & 63;
        int ri = H >> 9;                       // tile*NKT2 + kt
        int kt = ri % NKT2;
        int tile = ri / NKT2;                  // 0..27
        int g  = tile / NUT2, j = tile % NUT2;
        int up = j * 16 + (l & 15);
        int k  = kt * 32 + (l >> 4) * 8 + s;
        float v0 = 0.f, v1 = 0.f;
        if (up < HD2) {
            int r = g * HD2 + up;
            auto val2 = [&](int kk) -> float {
                if (kk < HD1) return W_ih2[r * HD1 + kk];
                if (kk < HD1 + HD2) return W_hh2[r * HD2 + (kk - HD1)];
                if (kk == HD1 + HD2) return b_ih2[r] + b_hh2[r];
                return 0.f;
            };
            v0 = val2(k); v1 = val2(k + 1);
        }
        w2f[d] = packh(v0, v1);
    }
}

// ---------------------------------------------------------------------------
// FUSED two-layer LSTM. 64 blocks x 768 threads (12 waves), 16 batches/block.
//
// R12 RATIONALE: R11's VGPR=76 with un-elidable volatile loads + zero spill
// proves the A-fragments live in AGPRs (unified file; rocprof VGPR_Count
// doesn't report AGPR) — the remat theory was a counter-reading artifact.
// Real model (consistent R6-R11): MfmaUtil 16.5%/VALUBusy ~80% on ACTIVE
// CUs -> VALU-ISSUE-bound; ~4500cy/iter of VALU vs ~920cy MFMA. Biggest
// consumers: full-precision f32 div in sigmoids (~10 ops each, 20/wave/iter)
// and per-iter B-frag address math with per-lane (gi<10) selects.
// Fixes: (1) rcp-based sigm/tanh; (2) MERGED B-buffer Hb[2][24*128]
// (relu-h1 groups 0-9, h2 groups 10-23, bias 1.0 @k=180) -> B-frag addr =
// loop-invariant lane base + compile-time kt*512; no selects;
// (3) #pragma unroll 2 so parity picks fold per copy.
// Parity (rederived for merged buffer): at iter i both roles WRITE parity
// i&1 (disjoint groups) and READ parity (i-1)&1. h1b (raw h1 + x/bias
// slots) identical discipline.
// ---------------------------------------------------------------------------
__global__ __launch_bounds__(768, 1)
void lstm_fused(const float* __restrict__ x,
                const _Float16* __restrict__ w1f,
                const _Float16* __restrict__ w2f,
                float* __restrict__ h2last)
{
    const int tid = threadIdx.x;
    const int l   = tid & 63;
    const int wv  = tid >> 6;              // 0..11
    const int b0  = blockIdx.x * NB2;
    const int bt  = l & 15;                // batch column (C/D col = lane&15)
    const int ro  = (l >> 4) << 2;         // unit offset  (C/D row = (lane>>4)*4+reg)
    const bool isL2 = (wv < 7);
    const int lane_base = ((l >> 4) << 7) + (bt << 3);   // (l>>4)*128 + bt*8

    __shared__ float    xs[T_STEPS * NB2];        // 32KB: x[t][bt] f32
    __shared__ _Float16 h1b[2][12 * 128];         // raw h1 + bias/x slots (K=96)
    __shared__ _Float16 Hb[2][24 * 128];          // MERGED: relu-h1 (0-9) + h2 (10-23)

    // ---- persistent A-fragments (volatile: kept live -> AGPR file) ----
    f16x8 a[4][NKT2];
    if (isL2) {
#pragma unroll
        for (int g = 0; g < 4; g++)
#pragma unroll
            for (int kt = 0; kt < NKT2; kt++)
                a[g][kt] = *(const volatile f16x8*)(w2f +
                    ((size_t)((g * NUT2 + wv) * NKT2 + kt) * 64 + l) * 8);
    } else {
        const int j1 = wv - 7;             // 0..4
#pragma unroll
        for (int g = 0; g < 4; g++)
#pragma unroll
            for (int kt = 0; kt < NKT1; kt++)
                a[g][kt] = *(const volatile f16x8*)(w1f +
                    ((size_t)((g * NUT1 + j1) * NKT1 + kt) * 64 + l) * 8);
    }

    const int u0 = isL2 ? (wv * 16 + ro) : ((wv - 7) * 16 + ro);
    const bool worker = isL2 ? (u0 < HD2) : true;

    float c[4] = {0.f, 0.f, 0.f, 0.f};

    // ---- init LDS ----
    for (int i = tid; i < 2 * 12 * 128 / 2; i += 768) ((unsigned int*)h1b)[i] = 0u;
    for (int i = tid; i < 2 * 24 * 128 / 2; i += 768) ((unsigned int*)Hb)[i]  = 0u;
    for (int idx = tid; idx < T_STEPS * NB2; idx += 768) {
        int tt = idx & (T_STEPS - 1), bb = idx >> 9;
        xs[tt * NB2 + bb] = x[((size_t)(b0 + bb)) * T_STEPS + tt];
    }
    __syncthreads();
    if (tid < NB2) {
        h1b[0][10 * 128 + tid * 8 + 0] = (_Float16)1.f;   // k=80: 1.0 (bias)
        h1b[1][10 * 128 + tid * 8 + 0] = (_Float16)1.f;
        h1b[1][10 * 128 + tid * 8 + 1] =                   // k=81: x(0), read at i=0
            (_Float16)x[((size_t)(b0 + tid)) * T_STEPS];
        Hb[0][22 * 128 + tid * 8 + 4] = (_Float16)1.f;    // k=180: 1.0 (bias)
        Hb[1][22 * 128 + tid * 8 + 4] = (_Float16)1.f;
    }
    __syncthreads();

#pragma unroll 2
    for (int i = 0; i <= T_STEPS; i++) {
        const int rp = (i - 1) & 1;            // read parity (folds per unrolled copy)
        const int wp = i & 1;                  // write parity
        if (isL2) {
            if (i >= 1) {
                const _Float16* bp = &Hb[rp][0] + lane_base;
                f16x8 bfr[NKT2];
#pragma unroll
                for (int kt = 0; kt < NKT2; kt++)
                    bfr[kt] = *(const f16x8*)(bp + kt * 512);   // imm offsets
                f32x4 acc[4];
#pragma unroll
                for (int g = 0; g < 4; g++) {
                    f32x4 z4 = {0.f, 0.f, 0.f, 0.f};
#pragma unroll
                    for (int kt = 0; kt < NKT2; kt++)
                        z4 = __builtin_amdgcn_mfma_f32_16x16x32_f16(
                                 a[g][kt], bfr[kt], z4, 0, 0, 0);
                    acc[g] = z4;
                }
                if (worker) {
                    f16x4 hh;
#pragma unroll
                    for (int r = 0; r < 4; r++) {
                        float gi = sigm(acc[0][r]);
                        float gf = sigm(acc[1][r]);
                        float gg = tanhf_(acc[2][r]);
                        float go = sigm(acc[3][r]);
                        c[r] = fmaf(gf, c[r], gi * gg);
                        float h = go * tanhf_(c[r]);
                        hh[r] = (_Float16)h;
                        if (i == T_STEPS)
                            h2last[(size_t)(b0 + bt) * HD2 + u0 + r] = fmaxf(h, 0.f);
                    }
                    int k0 = HD1 + u0;         // 80..176; k0&7 in {0,4}
                    *(f16x4*)&Hb[wp][(k0 >> 3) * 128 + (bt << 3) + (k0 & 7)] = hh;
                }
            }
        } else {
            if (i < T_STEPS) {
                const _Float16* bp = &h1b[rp][0] + lane_base;
                f16x8 bfr[NKT1];
#pragma unroll
                for (int kt = 0; kt < NKT1; kt++)
                    bfr[kt] = *(const f16x8*)(bp + kt * 512);
                f32x4 acc[4];
#pragma unroll
                for (int g = 0; g < 4; g++) {
                    f32x4 z4 = {0.f, 0.f, 0.f, 0.f};
#pragma unroll
                    for (int kt = 0; kt < NKT1; kt++)
                        z4 = __builtin_amdgcn_mfma_f32_16x16x32_f16(
                                 a[g][kt], bfr[kt], z4, 0, 0, 0);
                    acc[g] = z4;
                }
                f16x4 hraw, hrel;
#pragma unroll
                for (int r = 0; r < 4; r++) {
                    float gi = sigm(acc[0][r]);
                    float gf = sigm(acc[1][r]);
                    float gg = tanhf_(acc[2][r]);
                    float go = sigm(acc[3][r]);
                    c[r] = fmaf(gf, c[r], gi * gg);
                    float h = go * tanhf_(c[r]);
                    hraw[r] = (_Float16)h;
                    hrel[r] = (_Float16)fmaxf(h, 0.f);
                }
                int off = (u0 >> 3) * 128 + (bt << 3) + (u0 & 7);
                *(f16x4*)&h1b[wp][off] = hraw;
                *(f16x4*)&Hb[wp][off]  = hrel;           // groups 0..9
                if (wv == 7 && l < NB2 && i + 1 < T_STEPS)
                    h1b[wp][10 * 128 + l * 8 + 1] =
                        (_Float16)xs[(i + 1) * NB2 + l]; // x(i+1) slot
            }
        }
        __syncthreads();                       // single barrier per iter
    }
}

// ---------------------------------------------------------------------------
// Head: out[b] = W_l2 @ relu(W_l1 @ h2last[b] + b_l1) + b_l2
// ---------------------------------------------------------------------------
__global__ __launch_bounds__(64)
void head_kernel(const float* __restrict__ h2last,
                 const float* __restrict__ W_l1,
                 const float* __restrict__ b_l1,
                 const float* __restrict__ W_l2,
                 const float* __restrict__ b_l2,
                 float* __restrict__ out)
{
    int b = blockIdx.x * 64 + threadIdx.x;
    if (b >= BATCH) return;
    const float* h = h2last + (size_t)b * HD2;
    float o = b_l2[0];
#pragma unroll
    for (int u = 0; u < 10; u++) {
        float s = b_l1[u];
#pragma unroll
        for (int k = 0; k < HD2; k++) s = fmaf(W_l1[u * HD2 + k], h[k], s);
        o = fmaf(W_l2[u], fmaxf(s, 0.f), o);
    }
    out[b] = o;
}

extern "C" void kernel_launch(void* const* d_in, const int* in_sizes, int n_in,
                              void* d_out, int out_size, void* d_ws, size_t ws_size,
                              hipStream_t stream)
{
    const float* x     = (const float*)d_in[0];
    const float* W_ih1 = (const float*)d_in[1];
    const float* W_hh1 = (const float*)d_in[2];
    const float* b_ih1 = (const float*)d_in[3];
    const float* b_hh1 = (const float*)d_in[4];
    const float* W_ih2 = (const float*)d_in[5];
    const float* W_hh2 = (const float*)d_in[6];
    const float* b_ih2 = (const float*)d_in[7];
    const float* b_hh2 = (const float*)d_in[8];
    const float* W_l1  = (const float*)d_in[9];
    const float* b_l1  = (const float*)d_in[10];
    const float* W_l2  = (const float*)d_in[11];
    const float* b_l2  = (const float*)d_in[12];
    float* out = (float*)d_out;

    // ws layout: h2last f32 | w1f | w2f
    char* p = (char*)d_ws;
    float* h2last      = (float*)p;        p += (size_t)BATCH * HD2 * 4;
    unsigned int* w1fu = (unsigned int*)p; p += (size_t)W1F_DW * 4;
    unsigned int* w2fu = (unsigned int*)p;

    int prep_n = W1F_DW + W2F_DW;
    hipLaunchKernelGGL(prep_kernel, dim3((prep_n + 255) / 256), dim3(256), 0, stream,
                       W_hh1, W_ih2, W_hh2, W_ih1, b_ih1, b_hh1, b_ih2, b_hh2,
                       w1fu, w2fu);
    hipLaunchKernelGGL(lstm_fused, dim3(BATCH / NB2), dim3(768), 0, stream,
                       x, (const _Float16*)w1fu, (const _Float16*)w2fu, h2last);
    hipLaunchKernelGGL(head_kernel, dim3(BATCH / 64), dim3(64), 0, stream,
                       h2last, W_l1, b_l1, W_l2, b_l2, out);
}

// Round 13
// 639.655 us; speedup vs baseline: 2.2226x; 1.0650x over previous
//
#include <hip/hip_runtime.h>
#include <hip/hip_bf16.h>

#define T_STEPS 512
#define BATCH   1024
#define HD1     80
#define HD2     100
#define NB2     16                     // batches per block (MFMA N=16)
#define NGRP    (BATCH / NB2)          // 64 batch groups

// ---- MFMA fragment geometry (unchanged from R12) ----
#define NKT1    3
#define NUT1    5
#define NT1     (4 * NUT1)             // 20
#define NKT2    6
#define NUT2    7
#define NT2     (4 * NUT2)             // 28
#define W1F_DW  (NT1 * NKT1 * 64 * 4)  // 15360 dwords of lstm1 A-fragments
#define W2F_DW  (NT2 * NKT2 * 64 * 4)  // 43008 dwords of lstm2 A-fragments

// ---- chunked h1 handoff (R8-proven layout) ----
#define CH      16                     // steps per chunk
#define NCH     (T_STEPS / CH)         // 32 chunks
#define LINE_H  1280                   // halfs per (t,g) h1 line: 10 groups x 16 x 8

typedef _Float16 half2_t __attribute__((ext_vector_type(2)));
typedef _Float16 f16x4   __attribute__((ext_vector_type(4)));
typedef _Float16 f16x8   __attribute__((ext_vector_type(8)));
typedef float    f32x4   __attribute__((ext_vector_type(4)));

union HU { unsigned int u; half2_t h; };
static __device__ __forceinline__ unsigned int packh(float a, float b) {
    HU x; x.h.x = (_Float16)a; x.h.y = (_Float16)b; return x.u;
}

static __device__ __forceinline__ float sigm(float z) {
    return __builtin_amdgcn_rcpf(1.f + __expf(-z));
}
static __device__ __forceinline__ float tanhf_(float z) {
    return fmaf(2.f, __builtin_amdgcn_rcpf(1.f + __expf(-2.f * z)), -1.f);
}

static __device__ __forceinline__ void gld_lds16(const void* g, void* l) {
    __builtin_amdgcn_global_load_lds(
        (const __attribute__((address_space(1))) unsigned int*)g,
        (__attribute__((address_space(3))) unsigned int*)l, 16, 0, 0);
}

// ---------------------------------------------------------------------------
// Prep (R12 gauge) + flag zeroing (runs before lstm_split every launch/replay).
// ---------------------------------------------------------------------------
__global__ __launch_bounds__(256)
void prep_kernel(const float* __restrict__ W_hh1,
                 const float* __restrict__ W_ih2,
                 const float* __restrict__ W_hh2,
                 const float* __restrict__ W_ih1,
                 const float* __restrict__ b_ih1,
                 const float* __restrict__ b_hh1,
                 const float* __restrict__ b_ih2,
                 const float* __restrict__ b_hh2,
                 unsigned int* __restrict__ w1f,
                 unsigned int* __restrict__ w2f,
                 int* __restrict__ flags)
{
    int i = blockIdx.x * 256 + threadIdx.x;
    if (i < W1F_DW) {
        int H  = 2 * i;
        int s  = H & 7;
        int l  = (H >> 3) & 63;
        int ri = H >> 9;
        int kt = ri % NKT1;
        int tile = ri / NKT1;
        int g  = tile / NUT1, j = tile % NUT1;
        int r  = g * HD1 + j * 16 + (l & 15);
        int k  = kt * 32 + (l >> 4) * 8 + s;
        auto val1 = [&](int kk) -> float {
            if (kk < HD1) return W_hh1[r * HD1 + kk];
            if (kk == HD1) return b_ih1[r] + b_hh1[r];
            if (kk == HD1 + 1) return W_ih1[r];
            return 0.f;
        };
        w1f[i] = packh(val1(k), val1(k + 1));
    } else if (i < W1F_DW + W2F_DW) {
        int d  = i - W1F_DW;
        int H  = 2 * d;
        int s  = H & 7;
        int l  = (H >> 3) & 63;
        int ri = H >> 9;
        int kt = ri % NKT2;
        int tile = ri / NKT2;
        int g  = tile / NUT2, j = tile % NUT2;
        int up = j * 16 + (l & 15);
        int k  = kt * 32 + (l >> 4) * 8 + s;
        float v0 = 0.f, v1 = 0.f;
        if (up < HD2) {
            int r = g * HD2 + up;
            auto val2 = [&](int kk) -> float {
                if (kk < HD1) return W_ih2[r * HD1 + kk];
                if (kk < HD1 + HD2) return W_hh2[r * HD2 + (kk - HD1)];
                if (kk == HD1 + HD2) return b_ih2[r] + b_hh2[r];
                return 0.f;
            };
            v0 = val2(k); v1 = val2(k + 1);
        }
        w2f[d] = packh(v0, v1);
    } else if (i < W1F_DW + W2F_DW + NGRP * NCH) {
        flags[i - W1F_DW - W2F_DW] = 0;        // re-zeroed every launch
    }
}

// ---------------------------------------------------------------------------
// CONCURRENT LAYER-SPLIT two-layer LSTM. 128 blocks x 512 threads.
//
// R13 RATIONALE: R12 confirmed VALU/trans-issue-bound. Remaining floor: the
// ~1.9e9 transcendental ops (sigmoid/tanh) over only 64 active CUs (batch
// parallelism exhausted at 64 groups of 16). Only lever: MORE CUs. Split
// layers across blocks: bid<64 = L1 producer for group bid (own recurrence
// in LDS, writes relu(h1) 40KB chunks to global, R8-proven layout); bid>=64
// = L2 consumer (R12 L2 waves + R8 chunked gld_lds stager, gated on
// device-scope per-chunk flags). Per-CU trans demand halves -> ~2x.
// SAFETY: dependency is one-directional (consumer waits on producer only)
// => deadlock-free by construction; worst case = serial (~R12 parity).
// Memory model (G16): producer per-iter __syncthreads drains vmcnt, then
// __threadfence + agent-scope release store of flag; consumer agent-scope
// acquire poll (wave 7, non-blocking mid-chunk, blocking at boundary)
// before gld_lds. LDS 125KB/block => 1 block/CU => all 128 resident.
// ---------------------------------------------------------------------------
__global__ __launch_bounds__(512, 1)
void lstm_split(const float* __restrict__ x,
                const _Float16* __restrict__ w1f,
                const _Float16* __restrict__ w2f,
                _Float16* __restrict__ h1g,     // [NCH][NGRP][CH][LINE_H]
                int* __restrict__ flags,        // [NGRP][NCH]
                float* __restrict__ h2last)
{
    const int tid = threadIdx.x;
    const int l   = tid & 63;
    const int wv  = tid >> 6;              // 0..7
    const int bt  = l & 15;                // batch column (C/D col = lane&15)
    const int ro  = (l >> 4) << 2;         // unit offset  (C/D row)
    const int lane_base = ((l >> 4) << 7) + (bt << 3);

    __shared__ float    xs[T_STEPS * NB2];           // 32KB (producer)
    __shared__ _Float16 h1b[2][12 * 128];            // 6KB  (producer)
    __shared__ _Float16 chunkbuf[2][CH * LINE_H];    // 80KB (consumer)
    __shared__ _Float16 h2buf[2][14 * 128];          // 7KB  (consumer)

    if (blockIdx.x < NGRP) {
        // =================== PRODUCER: LSTM layer 1 =======================
        const int g  = blockIdx.x;
        const int b0 = g * NB2;
        const bool workerW = (wv < 5);
        const int u0 = wv * 16 + ro;       // 0..79 for workers

        f16x8 a[4][NKT1];
        if (workerW) {
#pragma unroll
            for (int gg = 0; gg < 4; gg++)
#pragma unroll
                for (int kt = 0; kt < NKT1; kt++)
                    a[gg][kt] = *(const volatile f16x8*)(w1f +
                        ((size_t)((gg * NUT1 + wv) * NKT1 + kt) * 64 + l) * 8);
        }
        float c[4] = {0.f, 0.f, 0.f, 0.f};

        for (int i = tid; i < 2 * 12 * 128 / 2; i += 512) ((unsigned int*)h1b)[i] = 0u;
        for (int idx = tid; idx < T_STEPS * NB2; idx += 512) {
            int tt = idx & (T_STEPS - 1), bb = idx >> 9;
            xs[tt * NB2 + bb] = x[((size_t)(b0 + bb)) * T_STEPS + tt];
        }
        __syncthreads();
        if (tid < NB2) {
            h1b[0][10 * 128 + tid * 8 + 0] = (_Float16)1.f;   // k=80: 1.0
            h1b[1][10 * 128 + tid * 8 + 0] = (_Float16)1.f;
            h1b[1][10 * 128 + tid * 8 + 1] = (_Float16)xs[0 * NB2 + tid]; // x(0)
        }
        __syncthreads();

#pragma unroll 2
        for (int i = 0; i < T_STEPS; i++) {
            const int rp = (i - 1) & 1, wp = i & 1;
            if (workerW) {
                const _Float16* bp = &h1b[rp][0] + lane_base;
                f16x8 bfr[NKT1];
#pragma unroll
                for (int kt = 0; kt < NKT1; kt++)
                    bfr[kt] = *(const f16x8*)(bp + kt * 512);
                f32x4 acc[4];
#pragma unroll
                for (int gg = 0; gg < 4; gg++) {
                    f32x4 z4 = {0.f, 0.f, 0.f, 0.f};
#pragma unroll
                    for (int kt = 0; kt < NKT1; kt++)
                        z4 = __builtin_amdgcn_mfma_f32_16x16x32_f16(
                                 a[gg][kt], bfr[kt], z4, 0, 0, 0);
                    acc[gg] = z4;
                }
                f16x4 hraw, hrel;
#pragma unroll
                for (int r = 0; r < 4; r++) {
                    float gi = sigm(acc[0][r]);
                    float gf = sigm(acc[1][r]);
                    float gg2 = tanhf_(acc[2][r]);
                    float go = sigm(acc[3][r]);
                    c[r] = fmaf(gf, c[r], gi * gg2);
                    float h = go * tanhf_(c[r]);
                    hraw[r] = (_Float16)h;
                    hrel[r] = (_Float16)fmaxf(h, 0.f);
                }
                int off = (u0 >> 3) * 128 + (bt << 3) + (u0 & 7);
                *(f16x4*)&h1b[wp][off] = hraw;
                // global chunk write (R8 layout)
                size_t goff = (((size_t)(i >> 4) * NGRP + g) * CH + (i & 15)) * LINE_H + off;
                *(f16x4*)(h1g + goff) = hrel;
            } else if (wv == 5 && l < NB2 && i + 1 < T_STEPS) {
                h1b[wp][10 * 128 + l * 8 + 1] = (_Float16)xs[(i + 1) * NB2 + l];
            }
            __syncthreads();               // drains chunk writes (vmcnt0)
            if ((i & 15) == 15 && tid == 0) {
                __threadfence();           // device-scope release of data
                __hip_atomic_store(&flags[g * NCH + (i >> 4)], 1,
                                   __ATOMIC_RELEASE, __HIP_MEMORY_SCOPE_AGENT);
            }
        }
    } else {
        // =================== CONSUMER: LSTM layer 2 =======================
        const int g  = blockIdx.x - NGRP;
        const int b0 = g * NB2;
        const bool workerWave = (wv < 7);
        const int u0 = wv * 16 + ro;
        const bool worker = workerWave && (u0 < HD2);

        f16x8 a[4][NKT2];
        if (workerWave) {
#pragma unroll
            for (int gg = 0; gg < 4; gg++)
#pragma unroll
                for (int kt = 0; kt < NKT2; kt++)
                    a[gg][kt] = *(const volatile f16x8*)(w2f +
                        ((size_t)((gg * NUT2 + wv) * NKT2 + kt) * 64 + l) * 8);
        }
        float c[4] = {0.f, 0.f, 0.f, 0.f};

        for (int i = tid; i < 2 * 14 * 128 / 2; i += 512) ((unsigned int*)h2buf)[i] = 0u;
        __syncthreads();
        if (tid < NB2) {
            h2buf[0][12 * 128 + tid * 8 + 4] = (_Float16)1.f;   // k=180: 1.0
            h2buf[1][12 * 128 + tid * 8 + 4] = (_Float16)1.f;
        }
        // prologue: wait for chunk 0, DMA it
        if (wv == 7) {
            while (__hip_atomic_load(&flags[g * NCH], __ATOMIC_ACQUIRE,
                                     __HIP_MEMORY_SCOPE_AGENT) == 0)
                __builtin_amdgcn_s_sleep(8);
            const _Float16* gsrc = h1g + (size_t)g * (CH * LINE_H) + l * 8;
#pragma unroll
            for (int q = 0; q < 40; q++)
                gld_lds16(gsrc + q * 512, &chunkbuf[0][q * 512]);
        }
        __syncthreads();                   // drains DMA; bias slots visible

        int cb = 0;
        bool nissued = false;
        for (int i = 0; i < T_STEPS; i++) {
            const int tc = i & (CH - 1);
            const int ch = i >> 4;
            if (workerWave) {
                const _Float16* ck  = &chunkbuf[cb][tc * LINE_H];
                const _Float16* h2p = &h2buf[i & 1][0];
                f16x8 bfr[NKT2];
#pragma unroll
                for (int kt = 0; kt < NKT2; kt++) {
                    int gi = kt * 4 + (l >> 4);
                    const _Float16* src = (gi < 10)
                        ? (ck + gi * 128 + (bt << 3))
                        : (h2p + (gi - 10) * 128 + (bt << 3));
                    bfr[kt] = *(const f16x8*)src;
                }
                f32x4 acc[4];
#pragma unroll
                for (int gg = 0; gg < 4; gg++) {
                    f32x4 z4 = {0.f, 0.f, 0.f, 0.f};
#pragma unroll
                    for (int kt = 0; kt < NKT2; kt++)
                        z4 = __builtin_amdgcn_mfma_f32_16x16x32_f16(
                                 a[gg][kt], bfr[kt], z4, 0, 0, 0);
                    acc[gg] = z4;
                }
                if (worker) {
                    f16x4 hh;
#pragma unroll
                    for (int r = 0; r < 4; r++) {
                        float gi = sigm(acc[0][r]);
                        float gf = sigm(acc[1][r]);
                        float gg2 = tanhf_(acc[2][r]);
                        float go = sigm(acc[3][r]);
                        c[r] = fmaf(gf, c[r], gi * gg2);
                        float h = go * tanhf_(c[r]);
                        hh[r] = (_Float16)h;
                        if (i == T_STEPS - 1)
                            h2last[(size_t)(b0 + bt) * HD2 + u0 + r] = fmaxf(h, 0.f);
                    }
                    int k0 = HD1 + u0;
                    *(f16x4*)&h2buf[(i + 1) & 1]
                        [((k0 >> 3) - 10) * 128 + (bt << 3) + (k0 & 7)] = hh;
                }
            } else {
                // stager wave 7: prefetch next chunk when its flag is up
                if (!nissued && ch + 1 < NCH) {
                    bool rdy = (__hip_atomic_load(&flags[g * NCH + ch + 1],
                                    __ATOMIC_ACQUIRE, __HIP_MEMORY_SCOPE_AGENT) != 0);
                    if (tc == CH - 1 && !rdy) {
                        while (__hip_atomic_load(&flags[g * NCH + ch + 1],
                                   __ATOMIC_ACQUIRE, __HIP_MEMORY_SCOPE_AGENT) == 0)
                            __builtin_amdgcn_s_sleep(8);
                        rdy = true;
                    }
                    if (rdy) {
                        const _Float16* gsrc = h1g +
                            ((size_t)(ch + 1) * NGRP + g) * (CH * LINE_H) + l * 8;
                        _Float16* dst = &chunkbuf[cb ^ 1][0];
#pragma unroll
                        for (int q = 0; q < 40; q++)
                            gld_lds16(gsrc + q * 512, dst + q * 512);
                        nissued = true;
                    }
                }
            }
            __syncthreads();               // single barrier/iter; drains stager DMA
            if (tc == CH - 1) { cb ^= 1; nissued = false; }
        }
    }
}

// ---------------------------------------------------------------------------
// Head: out[b] = W_l2 @ relu(W_l1 @ h2last[b] + b_l1) + b_l2
// ---------------------------------------------------------------------------
__global__ __launch_bounds__(64)
void head_kernel(const float* __restrict__ h2last,
                 const float* __restrict__ W_l1,
                 const float* __restrict__ b_l1,
                 const float* __restrict__ W_l2,
                 const float* __restrict__ b_l2,
                 float* __restrict__ out)
{
    int b = blockIdx.x * 64 + threadIdx.x;
    if (b >= BATCH) return;
    const float* h = h2last + (size_t)b * HD2;
    float o = b_l2[0];
#pragma unroll
    for (int u = 0; u < 10; u++) {
        float s = b_l1[u];
#pragma unroll
        for (int k = 0; k < HD2; k++) s = fmaf(W_l1[u * HD2 + k], h[k], s);
        o = fmaf(W_l2[u], fmaxf(s, 0.f), o);
    }
    out[b] = o;
}

extern "C" void kernel_launch(void* const* d_in, const int* in_sizes, int n_in,
                              void* d_out, int out_size, void* d_ws, size_t ws_size,
                              hipStream_t stream)
{
    const float* x     = (const float*)d_in[0];
    const float* W_ih1 = (const float*)d_in[1];
    const float* W_hh1 = (const float*)d_in[2];
    const float* b_ih1 = (const float*)d_in[3];
    const float* b_hh1 = (const float*)d_in[4];
    const float* W_ih2 = (const float*)d_in[5];
    const float* W_hh2 = (const float*)d_in[6];
    const float* b_ih2 = (const float*)d_in[7];
    const float* b_hh2 = (const float*)d_in[8];
    const float* W_l1  = (const float*)d_in[9];
    const float* b_l1  = (const float*)d_in[10];
    const float* W_l2  = (const float*)d_in[11];
    const float* b_l2  = (const float*)d_in[12];
    float* out = (float*)d_out;

    // ws layout: h2last f32 | w1f | w2f | flags | h1g chunks (84 MB)
    char* p = (char*)d_ws;
    float* h2last      = (float*)p;        p += (size_t)BATCH * HD2 * 4;
    unsigned int* w1fu = (unsigned int*)p; p += (size_t)W1F_DW * 4;
    unsigned int* w2fu = (unsigned int*)p; p += (size_t)W2F_DW * 4;
    int* flags         = (int*)p;          p += (size_t)NGRP * NCH * 4;
    _Float16* h1g      = (_Float16*)p;

    int prep_n = W1F_DW + W2F_DW + NGRP * NCH;
    hipLaunchKernelGGL(prep_kernel, dim3((prep_n + 255) / 256), dim3(256), 0, stream,
                       W_hh1, W_ih2, W_hh2, W_ih1, b_ih1, b_hh1, b_ih2, b_hh2,
                       w1fu, w2fu, flags);
    hipLaunchKernelGGL(lstm_split, dim3(2 * NGRP), dim3(512), 0, stream,
                       x, (const _Float16*)w1fu, (const _Float16*)w2fu,
                       h1g, flags, h2last);
    hipLaunchKernelGGL(head_kernel, dim3(BATCH / 64), dim3(64), 0, stream,
                       h2last, W_l1, b_l1, W_l2, b_l2, out);
}